// Round 3
// baseline (662.297 us; speedup 1.0000x reference)
//
#include <hip/hip_runtime.h>
#include <math.h>

// ---------------------------------------------------------------------------
// Precise45K CNN+QNN forward, fp32, fused.
//   k_convfused : conv1+conv2+conv3+adaptivepool entirely in LDS (4 samples/blk)
//   k_rowgemm16 : 16-row x full-N GEMM (512 blocks -> all 256 CUs, 2 blk/CU).
//                 Epilogues: PLAIN(bias+relu) / NORM(+row L2-normalize) /
//                 QSUM(signed square-sum). Optional A-synthesis
//                 A[m,k]=relu(q[m]*w[k]+b[k]) (head layer 1 never materialized).
//   k_rowgemm64 : 64-row variant (used only for tiny c4 layer, N=64)
//   k_buildU    : quantum circuit -> 256x256 orthogonal matrix U
//   k_head5     : final dot(64) + sigmoid
// ---------------------------------------------------------------------------

// ------------------------- fused conv stack --------------------------------
// conv1: [1,28,28]->relu[8,14,14] k5 s2 p2 ; conv2: ->relu[16,7,7] k3 s2 p1 ;
// conv3: ->relu[32,7,7] k3 s1 p1 ; adaptive pool 7->3 (bins start {0,2,4}, len 3)
template <int OY0, int OYN, int RB, int RN>
__device__ __forceinline__ void conv3_part(const float* __restrict__ xs,   // y2s[s], 784 floats
                                           const float* __restrict__ wl3,
                                           int co, float acc[4][7]) {
  for (int ci = 0; ci < 16; ++ci) {
    float xr[RN][7];
#pragma unroll
    for (int rr = 0; rr < RN; ++rr)
#pragma unroll
      for (int j = 0; j < 7; ++j) xr[rr][j] = xs[ci * 49 + (RB + rr) * 7 + j];
#pragma unroll
    for (int ky = 0; ky < 3; ++ky) {
      const float w0 = wl3[co * 144 + ci * 9 + ky * 3 + 0];
      const float w1 = wl3[co * 144 + ci * 9 + ky * 3 + 1];
      const float w2 = wl3[co * 144 + ci * 9 + ky * 3 + 2];
#pragma unroll
      for (int oi = 0; oi < OYN; ++oi) {
        const int y = OY0 + oi - 1 + ky;     // compile-time after unroll
        if (y >= 0 && y <= 6) {
          const int rr = y - RB;             // compile-time -> xr stays in regs
#pragma unroll
          for (int ox = 0; ox < 7; ++ox) {
            if (ox >= 1) acc[oi][ox] += w0 * xr[rr][ox - 1];
            acc[oi][ox] += w1 * xr[rr][ox];
            if (ox <= 5) acc[oi][ox] += w2 * xr[rr][ox + 1];
          }
        }
      }
    }
  }
}

__global__ __launch_bounds__(256) void k_convfused(
    const float* __restrict__ x,
    const float* __restrict__ w1, const float* __restrict__ b1,
    const float* __restrict__ w2, const float* __restrict__ b2,
    const float* __restrict__ w3, const float* __restrict__ b3,
    float* __restrict__ pooled) {
  __shared__ float wl1[200], bl1[8], wl2[1152], bl2[16], wl3[4608], bl3[32];
  __shared__ float y2s[4][784];
  // union: xin[4][784] (@0..3135) + y1s[4][1568] (@3136..9407); reused as y3s[4][1568] (@0)
  __shared__ float ubuf[9408];
  float(*xin)[784]  = reinterpret_cast<float(*)[784]>(ubuf);
  float(*y1s)[1568] = reinterpret_cast<float(*)[1568]>(ubuf + 3136);
  float(*y3s)[1568] = reinterpret_cast<float(*)[1568]>(ubuf);

  const int n0 = blockIdx.x * 4;
  const int tid = threadIdx.x;

  for (int i = tid; i < 200; i += 256) wl1[i] = w1[i];
  if (tid < 8) bl1[tid] = b1[tid];
  for (int i = tid; i < 1152; i += 256) wl2[i] = w2[i];
  if (tid < 16) bl2[tid] = b2[tid];
  for (int i = tid; i < 4608; i += 256) wl3[i] = w3[i];
  if (tid < 32) bl3[tid] = b3[tid];
  for (int i = tid; i < 3136; i += 256) {
    int s = i / 784, o = i % 784;
    xin[s][o] = x[(size_t)(n0 + s) * 784 + o];
  }
  __syncthreads();

  // ---- stage A: conv1 ----
  for (int idx = tid; idx < 4 * 1568; idx += 256) {
    int s = idx / 1568, o = idx % 1568;
    int co = o / 196, r = o % 196, oy = r / 14, ox = r % 14;
    float acc = bl1[co];
    for (int ky = 0; ky < 5; ++ky) {
      int y = oy * 2 - 2 + ky;
      if ((unsigned)y < 28u) {
        for (int kx = 0; kx < 5; ++kx) {
          int xx = ox * 2 - 2 + kx;
          if ((unsigned)xx < 28u) acc += wl1[co * 25 + ky * 5 + kx] * xin[s][y * 28 + xx];
        }
      }
    }
    y1s[s][o] = fmaxf(acc, 0.f);
  }
  __syncthreads();

  // ---- stage B: conv2 ---- thread = (s, co-pair, oy): 4*8*7 = 224 active
  if (tid < 224) {
    int s = tid / 56, r = tid % 56, cop = r / 7, oy = r % 7;
    int co0 = cop * 2;
    float acc0[7], acc1[7];
#pragma unroll
    for (int ox = 0; ox < 7; ++ox) { acc0[ox] = bl2[co0]; acc1[ox] = bl2[co0 + 1]; }
    for (int ci = 0; ci < 8; ++ci) {
#pragma unroll
      for (int ky = 0; ky < 3; ++ky) {
        int y = oy * 2 - 1 + ky;
        if ((unsigned)y < 14u) {
          float xr[14];
#pragma unroll
          for (int j = 0; j < 14; ++j) xr[j] = y1s[s][ci * 196 + y * 14 + j];
          float wa0 = wl2[co0 * 72 + ci * 9 + ky * 3 + 0];
          float wa1 = wl2[co0 * 72 + ci * 9 + ky * 3 + 1];
          float wa2 = wl2[co0 * 72 + ci * 9 + ky * 3 + 2];
          float wb0 = wl2[(co0 + 1) * 72 + ci * 9 + ky * 3 + 0];
          float wb1 = wl2[(co0 + 1) * 72 + ci * 9 + ky * 3 + 1];
          float wb2 = wl2[(co0 + 1) * 72 + ci * 9 + ky * 3 + 2];
#pragma unroll
          for (int ox = 0; ox < 7; ++ox) {
            // kx=0: xx=2ox-1 ; kx=1: 2ox ; kx=2: 2ox+1  (bounds compile-time)
            if (2 * ox - 1 >= 0) { acc0[ox] += wa0 * xr[2 * ox - 1]; acc1[ox] += wb0 * xr[2 * ox - 1]; }
            acc0[ox] += wa1 * xr[2 * ox];
            acc1[ox] += wb1 * xr[2 * ox];
            if (2 * ox + 1 < 14) { acc0[ox] += wa2 * xr[2 * ox + 1]; acc1[ox] += wb2 * xr[2 * ox + 1]; }
          }
        }
      }
    }
#pragma unroll
    for (int ox = 0; ox < 7; ++ox) {
      y2s[s][(co0 + 0) * 49 + oy * 7 + ox] = fmaxf(acc0[ox], 0.f);
      y2s[s][(co0 + 1) * 49 + oy * 7 + ox] = fmaxf(acc1[ox], 0.f);
    }
  }
  __syncthreads();

  // ---- stage C: conv3 ---- thread = (s, co, g): g=0 -> oy 0..3, g=1 -> oy 4..6
  {
    const int s = tid >> 6, co = (tid >> 1) & 31, g = tid & 1;
    float acc[4][7];
#pragma unroll
    for (int i = 0; i < 4; ++i)
#pragma unroll
      for (int ox = 0; ox < 7; ++ox) acc[i][ox] = bl3[co];
    if (g == 0) {
      conv3_part<0, 4, 0, 5>(&y2s[s][0], wl3, co, acc);
#pragma unroll
      for (int i = 0; i < 4; ++i)
#pragma unroll
        for (int ox = 0; ox < 7; ++ox)
          y3s[s][co * 49 + i * 7 + ox] = fmaxf(acc[i][ox], 0.f);
    } else {
      conv3_part<4, 3, 3, 4>(&y2s[s][0], wl3, co, acc);
#pragma unroll
      for (int i = 0; i < 3; ++i)
#pragma unroll
        for (int ox = 0; ox < 7; ++ox)
          y3s[s][co * 49 + (4 + i) * 7 + ox] = fmaxf(acc[i][ox], 0.f);
    }
  }
  __syncthreads();

  // ---- stage D: adaptive avg pool 7->3 (bins {0,2,4}+3) ----
  for (int idx = tid; idx < 1152; idx += 256) {
    int s = idx / 288, r = idx % 288, co = r / 9, p = r % 9, py = p / 3, px = p % 3;
    float v = 0.f;
#pragma unroll
    for (int dy = 0; dy < 3; ++dy)
#pragma unroll
      for (int dx = 0; dx < 3; ++dx)
        v += y3s[s][co * 49 + (2 * py + dy) * 7 + (2 * px + dx)];
    pooled[(size_t)(n0 + s) * 288 + co * 9 + p] = v * (1.f / 9.f);
  }
}

// ------------------- 16-row GEMM (full-N tiles, 512 blocks) ----------------
// C[16 x NT] per block, grid = M/16 = 512. A[M,K] * B[NT,K]^T. 256 threads.
// Thread (tr=tid>>5, tc=tid&31): rows tr*2+{0,1}; cols nc*128 + tc*4 + {0..3}.
// Row reductions live in an aligned 32-lane group (shfl_xor d=1..16).
// EP: 0=PLAIN(bias+relu), 1=NORM(bias+relu+row L2-normalize),
//     2=QSUM(q[m]=sum_{n<128}C^2 - sum_{n>=128}C^2; C not stored).
// ASYNTH: A[m,k]=relu(sq[m]*sw[k]+sb[k]) synthesized during staging.
template <int NT, int EP, bool ASYNTH>
__global__ __launch_bounds__(256) void k_rowgemm16(
    const float* __restrict__ A, const float* __restrict__ Bm,
    const float* __restrict__ bias, float* __restrict__ C,
    const float* __restrict__ sq, const float* __restrict__ sw,
    const float* __restrict__ sb, int K) {
  static_assert(NT == 128 || NT == 256, "NT");
  constexpr int NC = NT / 128;
  __shared__ float AT[32][17];
  __shared__ float BT[32][NT + 1];
  const int m0 = blockIdx.x * 16;
  const int tid = threadIdx.x;
  const int tr = tid >> 5, tc = tid & 31;
  float acc[2][NC][4];
#pragma unroll
  for (int i = 0; i < 2; ++i)
#pragma unroll
    for (int nc = 0; nc < NC; ++nc)
#pragma unroll
      for (int j = 0; j < 4; ++j) acc[i][nc][j] = 0.f;

  for (int k0 = 0; k0 < K; k0 += 32) {
#pragma unroll
    for (int e = 0; e < 2; ++e) {         // 16 rows x 32 k = 512 elems
      int idx = tid + e * 256;
      int mm = idx >> 5, kk = idx & 31;
      float av;
      if (ASYNTH) av = fmaxf(sq[m0 + mm] * sw[k0 + kk] + sb[k0 + kk], 0.f);
      else av = A[(size_t)(m0 + mm) * K + k0 + kk];
      AT[kk][mm] = av;
    }
#pragma unroll
    for (int e = 0; e < NT / 8; ++e) {    // NT rows x 32 k elems
      int idx = tid + e * 256;
      int nn = idx >> 5, kk = idx & 31;
      BT[kk][nn] = Bm[(size_t)nn * K + k0 + kk];
    }
    __syncthreads();
#pragma unroll
    for (int kk = 0; kk < 32; ++kk) {
      const float a0 = AT[kk][tr * 2 + 0];
      const float a1 = AT[kk][tr * 2 + 1];
#pragma unroll
      for (int nc = 0; nc < NC; ++nc) {
        float b[4];
#pragma unroll
        for (int j = 0; j < 4; ++j) b[j] = BT[kk][nc * 128 + tc * 4 + j];
#pragma unroll
        for (int j = 0; j < 4; ++j) {
          acc[0][nc][j] += a0 * b[j];
          acc[1][nc][j] += a1 * b[j];
        }
      }
    }
    __syncthreads();
  }

  if (EP == 2) {  // QSUM -> C is qv[M]; NT must be 256 (nc=0 -> +, nc=1 -> -)
    float qp[2] = {0.f, 0.f};
#pragma unroll
    for (int i = 0; i < 2; ++i)
#pragma unroll
      for (int nc = 0; nc < NC; ++nc)
#pragma unroll
        for (int j = 0; j < 4; ++j) {
          float v = acc[i][nc][j];
          qp[i] += (nc == 0) ? v * v : -v * v;
        }
#pragma unroll
    for (int i = 0; i < 2; ++i)
#pragma unroll
      for (int d = 1; d < 32; d <<= 1) qp[i] += __shfl_xor(qp[i], d, 64);
    if (tc == 0) {
#pragma unroll
      for (int i = 0; i < 2; ++i) C[m0 + tr * 2 + i] = qp[i];
    }
  } else if (EP == 1) {  // NORM
    float t[2][NC][4];
    float ss[2] = {0.f, 0.f};
#pragma unroll
    for (int i = 0; i < 2; ++i)
#pragma unroll
      for (int nc = 0; nc < NC; ++nc)
#pragma unroll
        for (int j = 0; j < 4; ++j) {
          float v = fmaxf(acc[i][nc][j] + bias[nc * 128 + tc * 4 + j], 0.f);
          t[i][nc][j] = v;
          ss[i] += v * v;
        }
#pragma unroll
    for (int i = 0; i < 2; ++i)
#pragma unroll
      for (int d = 1; d < 32; d <<= 1) ss[i] += __shfl_xor(ss[i], d, 64);
#pragma unroll
    for (int i = 0; i < 2; ++i) {
      float sc = 1.f / fmaxf(sqrtf(ss[i]), 1e-12f);
#pragma unroll
      for (int nc = 0; nc < NC; ++nc) {
        float4 v;
        v.x = t[i][nc][0] * sc; v.y = t[i][nc][1] * sc;
        v.z = t[i][nc][2] * sc; v.w = t[i][nc][3] * sc;
        *reinterpret_cast<float4*>(&C[(size_t)(m0 + tr * 2 + i) * NT + nc * 128 + tc * 4]) = v;
      }
    }
  } else {  // PLAIN
#pragma unroll
    for (int i = 0; i < 2; ++i)
#pragma unroll
      for (int nc = 0; nc < NC; ++nc) {
        float4 v;
        v.x = fmaxf(acc[i][nc][0] + bias[nc * 128 + tc * 4 + 0], 0.f);
        v.y = fmaxf(acc[i][nc][1] + bias[nc * 128 + tc * 4 + 1], 0.f);
        v.z = fmaxf(acc[i][nc][2] + bias[nc * 128 + tc * 4 + 2], 0.f);
        v.w = fmaxf(acc[i][nc][3] + bias[nc * 128 + tc * 4 + 3], 0.f);
        *reinterpret_cast<float4*>(&C[(size_t)(m0 + tr * 2 + i) * NT + nc * 128 + tc * 4]) = v;
      }
  }
}

// ------------------- 64-row GEMM (kept for tiny c4 layer) ------------------
template <int NT, int EP, bool ASYNTH>
__global__ __launch_bounds__(256) void k_rowgemm64(
    const float* __restrict__ A, const float* __restrict__ Bm,
    const float* __restrict__ bias, float* __restrict__ C,
    const float* __restrict__ sq, const float* __restrict__ sw,
    const float* __restrict__ sb, int K) {
  constexpr int NB = NT / 64;
  __shared__ float AT[32][65];
  __shared__ float BT[32][NT + 1];
  const int m0 = blockIdx.x * 64;
  const int tid = threadIdx.x;
  const int tr = tid >> 4, tc = tid & 15;
  float acc[4][NB][4];
#pragma unroll
  for (int i = 0; i < 4; ++i)
#pragma unroll
    for (int nb = 0; nb < NB; ++nb)
#pragma unroll
      for (int j = 0; j < 4; ++j) acc[i][nb][j] = 0.f;

  for (int k0 = 0; k0 < K; k0 += 32) {
#pragma unroll
    for (int e = 0; e < 8; ++e) {
      int idx = tid + e * 256;
      int mm = idx >> 5, kk = idx & 31;
      float av;
      if (ASYNTH) av = fmaxf(sq[m0 + mm] * sw[k0 + kk] + sb[k0 + kk], 0.f);
      else av = A[(size_t)(m0 + mm) * K + k0 + kk];
      AT[kk][mm] = av;
    }
#pragma unroll
    for (int e = 0; e < NB * 8; ++e) {
      int idx = tid + e * 256;
      int nn = idx >> 5, kk = idx & 31;
      BT[kk][nn] = Bm[(size_t)nn * K + k0 + kk];
    }
    __syncthreads();
#pragma unroll
    for (int kk = 0; kk < 32; ++kk) {
      float a[4];
#pragma unroll
      for (int i = 0; i < 4; ++i) a[i] = AT[kk][tr * 4 + i];
#pragma unroll
      for (int nb = 0; nb < NB; ++nb) {
        float b[4];
#pragma unroll
        for (int j = 0; j < 4; ++j) b[j] = BT[kk][nb * 64 + tc * 4 + j];
#pragma unroll
        for (int i = 0; i < 4; ++i)
#pragma unroll
          for (int j = 0; j < 4; ++j) acc[i][nb][j] += a[i] * b[j];
      }
    }
    __syncthreads();
  }

#pragma unroll
  for (int i = 0; i < 4; ++i)
#pragma unroll
    for (int nb = 0; nb < NB; ++nb) {
      float4 v;
      v.x = fmaxf(acc[i][nb][0] + bias[nb * 64 + tc * 4 + 0], 0.f);
      v.y = fmaxf(acc[i][nb][1] + bias[nb * 64 + tc * 4 + 1], 0.f);
      v.z = fmaxf(acc[i][nb][2] + bias[nb * 64 + tc * 4 + 2], 0.f);
      v.w = fmaxf(acc[i][nb][3] + bias[nb * 64 + tc * 4 + 3], 0.f);
      *reinterpret_cast<float4*>(&C[(size_t)(m0 + tr * 4 + i) * NT + nb * 64 + tc * 4]) = v;
    }
}

// ------------------------- quantum circuit -> U ----------------------------
// Block j simulates circuit on basis e_j. wire q acts on bit (7-q).
// Uw[n*256+k] = <n| U |k>   (B-matrix layout [N=256 out][K=256 in])
__global__ __launch_bounds__(128) void k_buildU(const float* __restrict__ qw,
                                                float* __restrict__ Uw) {
  __shared__ float st[256];
  const int j = blockIdx.x;
  const int tid = threadIdx.x;
  st[tid] = (tid == j) ? 1.f : 0.f;
  st[tid + 128] = (tid + 128 == j) ? 1.f : 0.f;
  __syncthreads();
  for (int l = 0; l < 7; ++l) {
    for (int q = 0; q < 8; ++q) {
      const float th = 0.5f * qw[l * 8 + q];
      const float c = cosf(th), s = sinf(th);
      const int m = 7 - q;
      const int lo = tid & ((1 << m) - 1);
      const int hi = tid >> m;
      const int i0 = (hi << (m + 1)) | lo;
      const int i1 = i0 | (1 << m);
      const float a = st[i0], bb = st[i1];   // pairs disjoint across threads
      st[i0] = c * a - s * bb;               // RY = [[c,-s],[s,c]]
      st[i1] = s * a + c * bb;
      __syncthreads();
    }
    for (int q = 0; q < 7; ++q) {
      const int mt = 6 - q;                  // target bit; control bit = mt+1
      float a0 = 0.f, a1 = 0.f;
      int i0 = 0, i1 = 0;
      if (tid < 64) {
        const int lo = tid & ((1 << mt) - 1);
        const int hi = tid >> mt;
        i0 = (hi << (mt + 2)) | (1 << (mt + 1)) | lo;   // control=1, target=0
        i1 = i0 | (1 << mt);
        a0 = st[i0]; a1 = st[i1];
      }
      __syncthreads();
      if (tid < 64) { st[i0] = a1; st[i1] = a0; }
      __syncthreads();
    }
  }
  for (int i = tid; i < 256; i += 128) Uw[i * 256 + j] = st[i];
}

// ------------------------- final layer -------------------------------------
__global__ __launch_bounds__(256) void k_head5(const float* __restrict__ h4,
                                               const float* __restrict__ w,
                                               const float* __restrict__ b,
                                               float* __restrict__ out) {
  const int row = blockIdx.x * 4 + (threadIdx.x >> 6);
  const int lane = threadIdx.x & 63;
  float s = h4[(size_t)row * 64 + lane] * w[lane];
#pragma unroll
  for (int d = 32; d > 0; d >>= 1) s += __shfl_xor(s, d, 64);
  if (lane == 0) out[row] = 1.f / (1.f + expf(-(s + b[0])));
}

// ---------------------------------------------------------------------------
extern "C" void kernel_launch(void* const* d_in, const int* in_sizes, int n_in,
                              void* d_out, int out_size, void* d_ws, size_t ws_size,
                              hipStream_t stream) {
  const float* x       = (const float*)d_in[0];
  const float* conv1_w = (const float*)d_in[1];
  const float* conv1_b = (const float*)d_in[2];
  const float* conv2_w = (const float*)d_in[3];
  const float* conv2_b = (const float*)d_in[4];
  const float* conv3_w = (const float*)d_in[5];
  const float* conv3_b = (const float*)d_in[6];
  const float* fc_w    = (const float*)d_in[7];
  const float* fc_b    = (const float*)d_in[8];
  const float* q_w     = (const float*)d_in[9];
  const float* c1_w    = (const float*)d_in[10];
  const float* c1_b    = (const float*)d_in[11];
  const float* c2_w    = (const float*)d_in[12];
  const float* c2_b    = (const float*)d_in[13];
  const float* c3_w    = (const float*)d_in[14];
  const float* c3_b    = (const float*)d_in[15];
  const float* c4_w    = (const float*)d_in[16];
  const float* c4_b    = (const float*)d_in[17];
  const float* c5_w    = (const float*)d_in[18];
  const float* c5_b    = (const float*)d_in[19];
  float* out = (float*)d_out;
  char* ws = (char*)d_ws;

  // workspace (bytes): total ~31.3 MB
  float* pooled = (float*)(ws + 0);          // 8192*288*4 = 9,437,184
  float* feat   = (float*)(ws + 9437184);    // 8192*256*4 = 8,388,608
  float* Uw     = (float*)(ws + 17825792);   // 256*256*4  =   262,144
  float* qv     = (float*)(ws + 18087936);   // 8192*4     =    32,768
  float* h2     = (float*)(ws + 18120704);   // 8192*256*4 = 8,388,608
  float* h3     = (float*)(ws + 26509312);   // 8192*128*4 = 4,194,304
  float* h4     = (float*)(ws + 30703616);   // 8192*64*4  = 2,097,152
  (void)in_sizes; (void)n_in; (void)out_size; (void)ws_size;

  k_convfused<<<2048, 256, 0, stream>>>(x, conv1_w, conv1_b, conv2_w, conv2_b,
                                        conv3_w, conv3_b, pooled);
  // fc (K=288) + relu + L2-normalize rows -> feat
  k_rowgemm16<256, 1, false><<<512, 256, 0, stream>>>(pooled, fc_w, fc_b, feat,
                                                      nullptr, nullptr, nullptr, 288);
  k_buildU<<<256, 128, 0, stream>>>(q_w, Uw);
  // phi = feat @ U^T, fused q = sum_{n<128} phi^2 - sum_{n>=128} phi^2 -> qv
  k_rowgemm16<256, 2, false><<<512, 256, 0, stream>>>(feat, Uw, nullptr, qv,
                                                      nullptr, nullptr, nullptr, 256);
  // h2 = relu( relu(q*c1w+c1b) @ c2^T + c2b )   (h1 synthesized, K=512)
  k_rowgemm16<256, 0, true><<<512, 256, 0, stream>>>(nullptr, c2_w, c2_b, h2,
                                                     qv, c1_w, c1_b, 512);
  // h3 = relu(h2 @ c3^T + c3b)  (K=256, N=128)
  k_rowgemm16<128, 0, false><<<512, 256, 0, stream>>>(h2, c3_w, c3_b, h3,
                                                      nullptr, nullptr, nullptr, 256);
  // h4 = relu(h3 @ c4^T + c4b)  (K=128, N=64)
  k_rowgemm64<64, 0, false><<<128, 256, 0, stream>>>(h3, c4_w, c4_b, h4,
                                                     nullptr, nullptr, nullptr, 128);
  k_head5<<<2048, 256, 0, stream>>>(h4, c5_w, c5_b, out);
}

// Round 4
// 479.623 us; speedup vs baseline: 1.3809x; 1.3809x over previous
//
#include <hip/hip_runtime.h>
#include <math.h>

// ---------------------------------------------------------------------------
// Precise45K CNN+QNN forward, fp32.
//  k_conv12    : conv1+conv2 fused in LDS (4 samples/blk), conflict-free
//                transposed weights, padded rows -> y2p [n][16][7][8] (HBM)
//  k_conv3pool : conv3 + adaptive pool, 8 samples/blk, weights w[k][co],
//                49 reg accumulators, pool from registers
//  k_rowgemm16 : 16-row x full-N GEMM, register-prefetch staging (global->reg
//                issued before compute, reg->LDS after barrier). Epilogues:
//                PLAIN / NORM(L2-normalize) / QSUM(signed square-sum);
//                ASYNTH synthesizes A[m,k]=relu(q[m]*w[k]+b[k]).
//  k_rowgemm64 : 64-row variant for tiny c4 layer (validated round-3 code)
//  k_buildU    : quantum circuit -> U, single wave, shuffle-only, no barriers
//  k_head5     : final dot(64) + sigmoid
// ---------------------------------------------------------------------------

// ------------------------- conv1 + conv2 -----------------------------------
// conv1: [1,28,28]->relu[8,14,14] k5 s2 p2 ; conv2: ->relu[16,7,7] k3 s2 p1
// y2p layout: [n][co<16][oy<7][8]  (896 floats/sample, x-padded to 8)
__global__ __launch_bounds__(256) void k_conv12(
    const float* __restrict__ x,
    const float* __restrict__ w1, const float* __restrict__ b1,
    const float* __restrict__ w2, const float* __restrict__ b2,
    float* __restrict__ y2p) {
  __shared__ float xin[4][784];          // 3136 fl
  __shared__ float y1p[4][8][14][16];    // 7168 fl (x-padded to 16)
  __shared__ float wl1[200], bl1[8];
  __shared__ float wl2t[72][16], bl2[16];  // [k=ci*9+kt][co] transposed
  const int n0 = blockIdx.x * 4;
  const int tid = threadIdx.x;

  for (int i = tid; i < 200; i += 256) wl1[i] = w1[i];
  if (tid < 8) bl1[tid] = b1[tid];
  for (int i = tid; i < 1152; i += 256) {
    int k = i >> 4, co = i & 15;
    wl2t[k][co] = w2[co * 72 + k];
  }
  if (tid < 16) bl2[tid] = b2[tid];
#pragma unroll
  for (int s = 0; s < 4; ++s)
    if (tid < 196)
      reinterpret_cast<float4*>(&xin[s][0])[tid] =
          reinterpret_cast<const float4*>(&x[(size_t)(n0 + s) * 784])[tid];
  __syncthreads();

  // ---- conv1 ---- thread = (s,co,oyh) : 4*8*7 = 224 active; 2 halves of oy
  if (tid < 224) {
    const int s = tid / 56, r = tid % 56, co = r / 7, oyh = r % 7;
    float wreg[25];
#pragma unroll
    for (int i = 0; i < 25; ++i) wreg[i] = wl1[co * 25 + i];
    const float bb = bl1[co];
#pragma unroll
    for (int half = 0; half < 2; ++half) {
      const int oy = oyh + half * 7;
      float acc[14];
#pragma unroll
      for (int ox = 0; ox < 14; ++ox) acc[ox] = bb;
#pragma unroll
      for (int ky = 0; ky < 5; ++ky) {
        const int y = oy * 2 - 2 + ky;
        if (y >= 0 && y < 28) {
          const float4* xp = reinterpret_cast<const float4*>(&xin[s][y * 28]);
          float xr[28];
#pragma unroll
          for (int v = 0; v < 7; ++v) {
            float4 q = xp[v];
            xr[v * 4 + 0] = q.x; xr[v * 4 + 1] = q.y;
            xr[v * 4 + 2] = q.z; xr[v * 4 + 3] = q.w;
          }
#pragma unroll
          for (int kx = 0; kx < 5; ++kx) {
            const float w = wreg[ky * 5 + kx];
#pragma unroll
            for (int ox = 0; ox < 14; ++ox) {
              const int xx = ox * 2 - 2 + kx;   // compile-time
              if (xx >= 0 && xx < 28) acc[ox] += w * xr[xx];
            }
          }
        }
      }
#pragma unroll
      for (int ox = 0; ox < 14; ++ox) y1p[s][co][oy][ox] = fmaxf(acc[ox], 0.f);
    }
  }
  __syncthreads();

  // ---- conv2 ---- thread = (s, co-pair, oy): 224 active
  if (tid < 224) {
    const int s = tid / 56, r = tid % 56, cop = r / 7, oy = r % 7;
    const int co0 = cop * 2;
    float acc0[7], acc1[7];
#pragma unroll
    for (int ox = 0; ox < 7; ++ox) { acc0[ox] = bl2[co0]; acc1[ox] = bl2[co0 + 1]; }
    for (int ci = 0; ci < 8; ++ci) {
#pragma unroll
      for (int ky = 0; ky < 3; ++ky) {
        const int y = oy * 2 - 1 + ky;
        if (y >= 0 && y < 14) {
          const float4* rp = reinterpret_cast<const float4*>(&y1p[s][ci][y][0]);
          float4 q0 = rp[0], q1 = rp[1], q2 = rp[2], q3 = rp[3];
          float xr[14] = {q0.x, q0.y, q0.z, q0.w, q1.x, q1.y, q1.z, q1.w,
                          q2.x, q2.y, q2.z, q2.w, q3.x, q3.y};
          const int kb = ci * 9 + ky * 3;
          const float wa0 = wl2t[kb + 0][co0],     wa1 = wl2t[kb + 1][co0],     wa2 = wl2t[kb + 2][co0];
          const float wb0 = wl2t[kb + 0][co0 + 1], wb1 = wl2t[kb + 1][co0 + 1], wb2 = wl2t[kb + 2][co0 + 1];
#pragma unroll
          for (int ox = 0; ox < 7; ++ox) {
            if (2 * ox - 1 >= 0) { acc0[ox] += wa0 * xr[2 * ox - 1]; acc1[ox] += wb0 * xr[2 * ox - 1]; }
            acc0[ox] += wa1 * xr[2 * ox];
            acc1[ox] += wb1 * xr[2 * ox];
            if (2 * ox + 1 < 14) { acc0[ox] += wa2 * xr[2 * ox + 1]; acc1[ox] += wb2 * xr[2 * ox + 1]; }
          }
        }
      }
    }
    float* o0 = &y2p[(size_t)(n0 + s) * 896 + (co0 + 0) * 56 + oy * 8];
    float* o1 = &y2p[(size_t)(n0 + s) * 896 + (co0 + 1) * 56 + oy * 8];
#pragma unroll
    for (int ox = 0; ox < 7; ++ox) {
      o0[ox] = fmaxf(acc0[ox], 0.f);
      o1[ox] = fmaxf(acc1[ox], 0.f);
    }
  }
}

// ------------------------- conv3 + adaptive pool ---------------------------
// in: y2p [n][16][7][8] ; out: pooled [n][288] (co*9 + p), bins start {0,2,4}
__global__ __launch_bounds__(256) void k_conv3pool(
    const float* __restrict__ y2p,
    const float* __restrict__ w3, const float* __restrict__ b3,
    float* __restrict__ pooled) {
  __shared__ float y2s[8][16][7][8];     // 7168 fl
  __shared__ float wl3t[144][32];        // [k=ci*9+kt][co]
  __shared__ float bl3[32];
  const int n0 = blockIdx.x * 8;
  const int tid = threadIdx.x;

  for (int i = tid; i < 4608; i += 256) {
    int k = i >> 5, co = i & 31;
    wl3t[k][co] = w3[co * 144 + k];
  }
  if (tid < 32) bl3[tid] = b3[tid];
#pragma unroll
  for (int s = 0; s < 8; ++s)
    if (tid < 224)
      reinterpret_cast<float4*>(&y2s[s][0][0][0])[tid] =
          reinterpret_cast<const float4*>(&y2p[(size_t)(n0 + s) * 896])[tid];
  __syncthreads();

  const int s = tid >> 5, co = tid & 31;
  float acc[49];
  {
    const float bb = bl3[co];
#pragma unroll
    for (int i = 0; i < 49; ++i) acc[i] = bb;
  }
  for (int ci = 0; ci < 16; ++ci) {
    float xr[7][7];
#pragma unroll
    for (int y = 0; y < 7; ++y) {
      const float4* rp = reinterpret_cast<const float4*>(&y2s[s][ci][y][0]);
      float4 qa = rp[0], qb = rp[1];
      xr[y][0] = qa.x; xr[y][1] = qa.y; xr[y][2] = qa.z; xr[y][3] = qa.w;
      xr[y][4] = qb.x; xr[y][5] = qb.y; xr[y][6] = qb.z;
    }
    float wreg[9];
#pragma unroll
    for (int k = 0; k < 9; ++k) wreg[k] = wl3t[ci * 9 + k][co];
#pragma unroll
    for (int ky = 0; ky < 3; ++ky)
#pragma unroll
      for (int kx = 0; kx < 3; ++kx) {
        const float w = wreg[ky * 3 + kx];
#pragma unroll
        for (int oy = 0; oy < 7; ++oy) {
          const int y = oy - 1 + ky;
          if (y >= 0 && y < 7) {
#pragma unroll
            for (int ox = 0; ox < 7; ++ox) {
              const int xx = ox - 1 + kx;
              if (xx >= 0 && xx < 7) acc[oy * 7 + ox] += w * xr[y][xx];
            }
          }
        }
      }
  }
#pragma unroll
  for (int i = 0; i < 49; ++i) acc[i] = fmaxf(acc[i], 0.f);
  float* out = pooled + (size_t)(n0 + s) * 288 + co * 9;
#pragma unroll
  for (int py = 0; py < 3; ++py)
#pragma unroll
    for (int px = 0; px < 3; ++px) {
      float v = 0.f;
#pragma unroll
      for (int dy = 0; dy < 3; ++dy)
#pragma unroll
        for (int dx = 0; dx < 3; ++dx) v += acc[(2 * py + dy) * 7 + (2 * px + dx)];
      out[py * 3 + px] = v * (1.f / 9.f);
    }
}

// ------------------- 16-row GEMM with register-prefetch staging ------------
// C[16 x NT] per block, grid = M/16 = 512. A[M,K] * B[NT,K]^T. 256 threads.
// Thread (tr=tid>>5, tc=tid&31): rows tr*2+{0,1}; cols nc*128 + tc*4 + {0..3}.
// EP: 0=PLAIN(bias+relu), 1=NORM(bias+relu+row L2-normalize),
//     2=QSUM(q[m]=sum_{n<128}C^2 - sum_{n>=128}C^2; C not stored).
// ASYNTH: A[m,k]=relu(sq[m]*sw[k]+sb[k]) synthesized during staging.
template <int NT, int EP, bool ASYNTH>
__global__ __launch_bounds__(256) void k_rowgemm16(
    const float* __restrict__ A, const float* __restrict__ Bm,
    const float* __restrict__ bias, float* __restrict__ C,
    const float* __restrict__ sq, const float* __restrict__ sw,
    const float* __restrict__ sb, int K) {
  static_assert(NT == 128 || NT == 256, "NT");
  constexpr int NC = NT / 128;
  constexpr int NB4 = NT / 32;   // float4 B-loads per thread per K-step
  __shared__ float AT[32][17];
  __shared__ float BT[32][NT + 1];
  const int m0 = blockIdx.x * 16;
  const int tid = threadIdx.x;
  const int tr = tid >> 5, tc = tid & 31;

  float ra[2];
  float4 rb[NB4];

  auto loadAB = [&](int k0) {
#pragma unroll
    for (int e = 0; e < 2; ++e) {
      const int idx = tid + e * 256;
      const int mm = idx >> 5, kk = idx & 31;
      if (ASYNTH) ra[e] = fmaxf(sq[m0 + mm] * sw[k0 + kk] + sb[k0 + kk], 0.f);
      else ra[e] = A[(size_t)(m0 + mm) * K + k0 + kk];
    }
#pragma unroll
    for (int e = 0; e < NB4; ++e) {
      const int idx4 = tid + e * 256;
      const int nn = idx4 >> 3, kq = idx4 & 7;
      rb[e] = *reinterpret_cast<const float4*>(&Bm[(size_t)nn * K + k0 + kq * 4]);
    }
  };
  auto storeAB = [&]() {
#pragma unroll
    for (int e = 0; e < 2; ++e) {
      const int idx = tid + e * 256;
      AT[idx & 31][idx >> 5] = ra[e];
    }
#pragma unroll
    for (int e = 0; e < NB4; ++e) {
      const int idx4 = tid + e * 256;
      const int nn = idx4 >> 3, kq = idx4 & 7;
      BT[kq * 4 + 0][nn] = rb[e].x;
      BT[kq * 4 + 1][nn] = rb[e].y;
      BT[kq * 4 + 2][nn] = rb[e].z;
      BT[kq * 4 + 3][nn] = rb[e].w;
    }
  };

  float acc[2][NC][4];
#pragma unroll
  for (int i = 0; i < 2; ++i)
#pragma unroll
    for (int nc = 0; nc < NC; ++nc)
#pragma unroll
      for (int j = 0; j < 4; ++j) acc[i][nc][j] = 0.f;

  loadAB(0);
  for (int k0 = 0; k0 < K; k0 += 32) {
    __syncthreads();           // previous compute done before LDS overwrite
    storeAB();
    __syncthreads();
    if (k0 + 32 < K) loadAB(k0 + 32);   // issue next loads under compute
#pragma unroll
    for (int kk = 0; kk < 32; ++kk) {
      const float a0 = AT[kk][tr * 2 + 0];
      const float a1 = AT[kk][tr * 2 + 1];
#pragma unroll
      for (int nc = 0; nc < NC; ++nc) {
        float b[4];
#pragma unroll
        for (int j = 0; j < 4; ++j) b[j] = BT[kk][nc * 128 + tc * 4 + j];
#pragma unroll
        for (int j = 0; j < 4; ++j) {
          acc[0][nc][j] += a0 * b[j];
          acc[1][nc][j] += a1 * b[j];
        }
      }
    }
  }

  if (EP == 2) {  // QSUM -> C is qv[M]; cols<128 +, cols>=128 -
    float qp[2] = {0.f, 0.f};
#pragma unroll
    for (int i = 0; i < 2; ++i)
#pragma unroll
      for (int nc = 0; nc < NC; ++nc)
#pragma unroll
        for (int j = 0; j < 4; ++j) {
          const float v = acc[i][nc][j];
          qp[i] += (nc == 0) ? v * v : -v * v;
        }
#pragma unroll
    for (int i = 0; i < 2; ++i)
#pragma unroll
      for (int d = 1; d < 32; d <<= 1) qp[i] += __shfl_xor(qp[i], d, 64);
    if (tc == 0) {
#pragma unroll
      for (int i = 0; i < 2; ++i) C[m0 + tr * 2 + i] = qp[i];
    }
  } else if (EP == 1) {  // NORM
    float t[2][NC][4];
    float ss[2] = {0.f, 0.f};
#pragma unroll
    for (int i = 0; i < 2; ++i)
#pragma unroll
      for (int nc = 0; nc < NC; ++nc)
#pragma unroll
        for (int j = 0; j < 4; ++j) {
          const float v = fmaxf(acc[i][nc][j] + bias[nc * 128 + tc * 4 + j], 0.f);
          t[i][nc][j] = v;
          ss[i] += v * v;
        }
#pragma unroll
    for (int i = 0; i < 2; ++i)
#pragma unroll
      for (int d = 1; d < 32; d <<= 1) ss[i] += __shfl_xor(ss[i], d, 64);
#pragma unroll
    for (int i = 0; i < 2; ++i) {
      const float sc = 1.f / fmaxf(sqrtf(ss[i]), 1e-12f);
#pragma unroll
      for (int nc = 0; nc < NC; ++nc) {
        float4 v;
        v.x = t[i][nc][0] * sc; v.y = t[i][nc][1] * sc;
        v.z = t[i][nc][2] * sc; v.w = t[i][nc][3] * sc;
        *reinterpret_cast<float4*>(&C[(size_t)(m0 + tr * 2 + i) * NT + nc * 128 + tc * 4]) = v;
      }
    }
  } else {  // PLAIN
#pragma unroll
    for (int i = 0; i < 2; ++i)
#pragma unroll
      for (int nc = 0; nc < NC; ++nc) {
        float4 v;
        v.x = fmaxf(acc[i][nc][0] + bias[nc * 128 + tc * 4 + 0], 0.f);
        v.y = fmaxf(acc[i][nc][1] + bias[nc * 128 + tc * 4 + 1], 0.f);
        v.z = fmaxf(acc[i][nc][2] + bias[nc * 128 + tc * 4 + 2], 0.f);
        v.w = fmaxf(acc[i][nc][3] + bias[nc * 128 + tc * 4 + 3], 0.f);
        *reinterpret_cast<float4*>(&C[(size_t)(m0 + tr * 2 + i) * NT + nc * 128 + tc * 4]) = v;
      }
  }
}

// ------------------- 64-row GEMM (tiny c4 layer; validated) ----------------
template <int NT>
__global__ __launch_bounds__(256) void k_rowgemm64(
    const float* __restrict__ A, const float* __restrict__ Bm,
    const float* __restrict__ bias, float* __restrict__ C, int K) {
  constexpr int NB = NT / 64;
  __shared__ float AT[32][65];
  __shared__ float BT[32][NT + 1];
  const int m0 = blockIdx.x * 64;
  const int tid = threadIdx.x;
  const int tr = tid >> 4, tc = tid & 15;
  float acc[4][NB][4];
#pragma unroll
  for (int i = 0; i < 4; ++i)
#pragma unroll
    for (int nb = 0; nb < NB; ++nb)
#pragma unroll
      for (int j = 0; j < 4; ++j) acc[i][nb][j] = 0.f;

  for (int k0 = 0; k0 < K; k0 += 32) {
#pragma unroll
    for (int e = 0; e < 8; ++e) {
      int idx = tid + e * 256;
      int mm = idx >> 5, kk = idx & 31;
      AT[kk][mm] = A[(size_t)(m0 + mm) * K + k0 + kk];
    }
#pragma unroll
    for (int e = 0; e < NB * 8; ++e) {
      int idx = tid + e * 256;
      int nn = idx >> 5, kk = idx & 31;
      BT[kk][nn] = Bm[(size_t)nn * K + k0 + kk];
    }
    __syncthreads();
#pragma unroll
    for (int kk = 0; kk < 32; ++kk) {
      float a[4];
#pragma unroll
      for (int i = 0; i < 4; ++i) a[i] = AT[kk][tr * 4 + i];
#pragma unroll
      for (int nb = 0; nb < NB; ++nb) {
        float b[4];
#pragma unroll
        for (int j = 0; j < 4; ++j) b[j] = BT[kk][nb * 64 + tc * 4 + j];
#pragma unroll
        for (int i = 0; i < 4; ++i)
#pragma unroll
          for (int j = 0; j < 4; ++j) acc[i][nb][j] += a[i] * b[j];
      }
    }
    __syncthreads();
  }
#pragma unroll
  for (int i = 0; i < 4; ++i)
#pragma unroll
    for (int nb = 0; nb < NB; ++nb) {
      float4 v;
      v.x = fmaxf(acc[i][nb][0] + bias[nb * 64 + tc * 4 + 0], 0.f);
      v.y = fmaxf(acc[i][nb][1] + bias[nb * 64 + tc * 4 + 1], 0.f);
      v.z = fmaxf(acc[i][nb][2] + bias[nb * 64 + tc * 4 + 2], 0.f);
      v.w = fmaxf(acc[i][nb][3] + bias[nb * 64 + tc * 4 + 3], 0.f);
      *reinterpret_cast<float4*>(&C[(size_t)(m0 + tr * 4 + i) * NT + nb * 64 + tc * 4]) = v;
    }
}

// ------------------------- quantum circuit -> U ----------------------------
// Single-wave, shuffle-only. Block j = basis e_j; thread t owns states
// {t, 64+t, 128+t, 192+t} (bit7,bit6 = register index; bits5..0 = lane).
// wire q acts on bit m=7-q. Uw[i*256+j] = <i|U|e_j>.
__global__ __launch_bounds__(64) void k_buildU(const float* __restrict__ qw,
                                               float* __restrict__ Uw) {
  const int j = blockIdx.x;
  const int t = threadIdx.x;
  float a0 = (t == j) ? 1.f : 0.f;
  float a1 = (64 + t == j) ? 1.f : 0.f;
  float a2 = (128 + t == j) ? 1.f : 0.f;
  float a3 = (192 + t == j) ? 1.f : 0.f;
  for (int l = 0; l < 7; ++l) {
#pragma unroll
    for (int q = 0; q < 8; ++q) {
      const float th = 0.5f * qw[l * 8 + q];
      const float c = cosf(th), s = sinf(th);
      const int m = 7 - q;      // compile-time after unroll
      if (m == 7) {             // pairs (a0,a2),(a1,a3)
        const float n0 = c * a0 - s * a2, n2 = s * a0 + c * a2;
        const float n1 = c * a1 - s * a3, n3 = s * a1 + c * a3;
        a0 = n0; a2 = n2; a1 = n1; a3 = n3;
      } else if (m == 6) {      // pairs (a0,a1),(a2,a3)
        const float n0 = c * a0 - s * a1, n1 = s * a0 + c * a1;
        const float n2 = c * a2 - s * a3, n3 = s * a2 + c * a3;
        a0 = n0; a1 = n1; a2 = n2; a3 = n3;
      } else {                  // cross-lane pair
        const float p0 = __shfl_xor(a0, 1 << m, 64);
        const float p1 = __shfl_xor(a1, 1 << m, 64);
        const float p2 = __shfl_xor(a2, 1 << m, 64);
        const float p3 = __shfl_xor(a3, 1 << m, 64);
        const float sgn = ((t >> m) & 1) ? s : -s;   // i0: c*a - s*p ; i1: c*a + s*p
        a0 = c * a0 + sgn * p0; a1 = c * a1 + sgn * p1;
        a2 = c * a2 + sgn * p2; a3 = c * a3 + sgn * p3;
      }
    }
#pragma unroll
    for (int q = 0; q < 7; ++q) {   // CNOT ctrl bit mc=7-q, tgt bit mt=mc-1
      const int mc = 7 - q, mt = mc - 1;
      if (mc == 7) {            // ctrl=bit7 -> a2,a3 ; flip bit6 -> swap a2<->a3
        const float tmp = a2; a2 = a3; a3 = tmp;
      } else if (mc == 6) {     // ctrl=bit6 -> a1,a3 ; flip lane bit5
        a1 = __shfl_xor(a1, 32, 64);
        a3 = __shfl_xor(a3, 32, 64);
      } else {                  // both bits in lane
        const float p0 = __shfl_xor(a0, 1 << mt, 64);
        const float p1 = __shfl_xor(a1, 1 << mt, 64);
        const float p2 = __shfl_xor(a2, 1 << mt, 64);
        const float p3 = __shfl_xor(a3, 1 << mt, 64);
        if ((t >> mc) & 1) { a0 = p0; a1 = p1; a2 = p2; a3 = p3; }
      }
    }
  }
  Uw[(0 * 64 + t) * 256 + j] = a0;
  Uw[(1 * 64 + t) * 256 + j] = a1;
  Uw[(2 * 64 + t) * 256 + j] = a2;
  Uw[(3 * 64 + t) * 256 + j] = a3;
}

// ------------------------- final layer -------------------------------------
__global__ __launch_bounds__(256) void k_head5(const float* __restrict__ h4,
                                               const float* __restrict__ w,
                                               const float* __restrict__ b,
                                               float* __restrict__ out) {
  const int row = blockIdx.x * 4 + (threadIdx.x >> 6);
  const int lane = threadIdx.x & 63;
  float s = h4[(size_t)row * 64 + lane] * w[lane];
#pragma unroll
  for (int d = 32; d > 0; d >>= 1) s += __shfl_xor(s, d, 64);
  if (lane == 0) out[row] = 1.f / (1.f + expf(-(s + b[0])));
}

// ---------------------------------------------------------------------------
extern "C" void kernel_launch(void* const* d_in, const int* in_sizes, int n_in,
                              void* d_out, int out_size, void* d_ws, size_t ws_size,
                              hipStream_t stream) {
  const float* x       = (const float*)d_in[0];
  const float* conv1_w = (const float*)d_in[1];
  const float* conv1_b = (const float*)d_in[2];
  const float* conv2_w = (const float*)d_in[3];
  const float* conv2_b = (const float*)d_in[4];
  const float* conv3_w = (const float*)d_in[5];
  const float* conv3_b = (const float*)d_in[6];
  const float* fc_w    = (const float*)d_in[7];
  const float* fc_b    = (const float*)d_in[8];
  const float* q_w     = (const float*)d_in[9];
  const float* c1_w    = (const float*)d_in[10];
  const float* c1_b    = (const float*)d_in[11];
  const float* c2_w    = (const float*)d_in[12];
  const float* c2_b    = (const float*)d_in[13];
  const float* c3_w    = (const float*)d_in[14];
  const float* c3_b    = (const float*)d_in[15];
  const float* c4_w    = (const float*)d_in[16];
  const float* c4_b    = (const float*)d_in[17];
  const float* c5_w    = (const float*)d_in[18];
  const float* c5_b    = (const float*)d_in[19];
  float* out = (float*)d_out;
  char* ws = (char*)d_ws;

  // workspace layout (peak 38.8 MB): y2p region recycled after conv3pool.
  float* y2p    = (float*)(ws + 0);          // 8192*896*4 = 29,360,128
  float* pooled = (float*)(ws + 29360128);   // 8192*288*4 =  9,437,184 (ends 38.8MB)
  float* feat   = (float*)(ws + 0);          // 8192*256*4 =  8,388,608 (y2p dead)
  float* Uw     = (float*)(ws + 8388608);    // 256*256*4  =    262,144
  float* qv     = (float*)(ws + 8650752);    // 8192*4     =     32,768
  float* h2     = (float*)(ws + 8683520);    // 8192*256*4 =  8,388,608
  float* h3     = (float*)(ws + 17072128);   // 8192*128*4 =  4,194,304
  float* h4     = (float*)(ws + 21266432);   // 8192*64*4  =  2,097,152
  (void)in_sizes; (void)n_in; (void)out_size; (void)ws_size;

  k_conv12<<<2048, 256, 0, stream>>>(x, conv1_w, conv1_b, conv2_w, conv2_b, y2p);
  k_conv3pool<<<1024, 256, 0, stream>>>(y2p, conv3_w, conv3_b, pooled);
  // fc (K=288) + relu + L2-normalize rows -> feat
  k_rowgemm16<256, 1, false><<<512, 256, 0, stream>>>(pooled, fc_w, fc_b, feat,
                                                      nullptr, nullptr, nullptr, 288);
  k_buildU<<<256, 64, 0, stream>>>(q_w, Uw);
  // phi = feat @ U^T fused with q = sum_{n<128} phi^2 - sum_{n>=128} phi^2
  k_rowgemm16<256, 2, false><<<512, 256, 0, stream>>>(feat, Uw, nullptr, qv,
                                                      nullptr, nullptr, nullptr, 256);
  // h2 = relu( relu(q*c1w+c1b) @ c2^T + c2b )  (h1 synthesized, K=512)
  k_rowgemm16<256, 0, true><<<512, 256, 0, stream>>>(nullptr, c2_w, c2_b, h2,
                                                     qv, c1_w, c1_b, 512);
  // h3 = relu(h2 @ c3^T + c3b)  (K=256, N=128)
  k_rowgemm16<128, 0, false><<<512, 256, 0, stream>>>(h2, c3_w, c3_b, h3,
                                                      nullptr, nullptr, nullptr, 256);
  // h4 = relu(h3 @ c4^T + c4b)  (K=128, N=64)
  k_rowgemm64<64><<<128, 256, 0, stream>>>(h3, c4_w, c4_b, h4, 128);
  k_head5<<<2048, 256, 0, stream>>>(h4, c5_w, c5_b, out);
}

// Round 6
// 366.604 us; speedup vs baseline: 1.8066x; 1.3083x over previous
//
#include <hip/hip_runtime.h>
#include <math.h>

// ---------------------------------------------------------------------------
// Precise45K CNN+QNN forward, fp32.
//  k_conv12    : conv1+conv2 fused in LDS (4 samples/blk) -> y2p [n][16][7][8]
//  k_conv3pool : conv3 + adaptive pool, 8 samples/blk
//  k_rowgemm16 : 16-row x full-N GEMM, register-prefetch staging, VECTORIZED
//                LDS fragment reads (stride NT+4 -> 16B-aligned, conflict-free
//                b128). Epilogues: PLAIN / NORM / QSUM; ASYNTH synthesizes
//                A[m,k]=relu(q[m]*w[k]+b[k]).
//  k_rowgemm64 : 64-row variant for tiny c4 layer, vectorized reads
//  k_buildU    : quantum circuit -> U, single wave, shuffle-only
//  k_head5     : final dot(64) + sigmoid
// ---------------------------------------------------------------------------

// ------------------------- conv1 + conv2 -----------------------------------
__global__ __launch_bounds__(256) void k_conv12(
    const float* __restrict__ x,
    const float* __restrict__ w1, const float* __restrict__ b1,
    const float* __restrict__ w2, const float* __restrict__ b2,
    float* __restrict__ y2p) {
  __shared__ float xin[4][784];
  __shared__ float y1p[4][8][14][16];
  __shared__ float wl1[200], bl1[8];
  __shared__ float wl2t[72][16], bl2[16];
  const int n0 = blockIdx.x * 4;
  const int tid = threadIdx.x;

  for (int i = tid; i < 200; i += 256) wl1[i] = w1[i];
  if (tid < 8) bl1[tid] = b1[tid];
  for (int i = tid; i < 1152; i += 256) {
    int k = i >> 4, co = i & 15;
    wl2t[k][co] = w2[co * 72 + k];
  }
  if (tid < 16) bl2[tid] = b2[tid];
#pragma unroll
  for (int s = 0; s < 4; ++s)
    if (tid < 196)
      reinterpret_cast<float4*>(&xin[s][0])[tid] =
          reinterpret_cast<const float4*>(&x[(size_t)(n0 + s) * 784])[tid];
  __syncthreads();

  if (tid < 224) {
    const int s = tid / 56, r = tid % 56, co = r / 7, oyh = r % 7;
    float wreg[25];
#pragma unroll
    for (int i = 0; i < 25; ++i) wreg[i] = wl1[co * 25 + i];
    const float bb = bl1[co];
#pragma unroll
    for (int half = 0; half < 2; ++half) {
      const int oy = oyh + half * 7;
      float acc[14];
#pragma unroll
      for (int ox = 0; ox < 14; ++ox) acc[ox] = bb;
#pragma unroll
      for (int ky = 0; ky < 5; ++ky) {
        const int y = oy * 2 - 2 + ky;
        if (y >= 0 && y < 28) {
          const float4* xp = reinterpret_cast<const float4*>(&xin[s][y * 28]);
          float xr[28];
#pragma unroll
          for (int v = 0; v < 7; ++v) {
            float4 q = xp[v];
            xr[v * 4 + 0] = q.x; xr[v * 4 + 1] = q.y;
            xr[v * 4 + 2] = q.z; xr[v * 4 + 3] = q.w;
          }
#pragma unroll
          for (int kx = 0; kx < 5; ++kx) {
            const float w = wreg[ky * 5 + kx];
#pragma unroll
            for (int ox = 0; ox < 14; ++ox) {
              const int xx = ox * 2 - 2 + kx;
              if (xx >= 0 && xx < 28) acc[ox] += w * xr[xx];
            }
          }
        }
      }
#pragma unroll
      for (int ox = 0; ox < 14; ++ox) y1p[s][co][oy][ox] = fmaxf(acc[ox], 0.f);
    }
  }
  __syncthreads();

  if (tid < 224) {
    const int s = tid / 56, r = tid % 56, cop = r / 7, oy = r % 7;
    const int co0 = cop * 2;
    float acc0[7], acc1[7];
#pragma unroll
    for (int ox = 0; ox < 7; ++ox) { acc0[ox] = bl2[co0]; acc1[ox] = bl2[co0 + 1]; }
    for (int ci = 0; ci < 8; ++ci) {
#pragma unroll
      for (int ky = 0; ky < 3; ++ky) {
        const int y = oy * 2 - 1 + ky;
        if (y >= 0 && y < 14) {
          const float4* rp = reinterpret_cast<const float4*>(&y1p[s][ci][y][0]);
          float4 q0 = rp[0], q1 = rp[1], q2 = rp[2], q3 = rp[3];
          float xr[14] = {q0.x, q0.y, q0.z, q0.w, q1.x, q1.y, q1.z, q1.w,
                          q2.x, q2.y, q2.z, q2.w, q3.x, q3.y};
          const int kb = ci * 9 + ky * 3;
          const float wa0 = wl2t[kb + 0][co0],     wa1 = wl2t[kb + 1][co0],     wa2 = wl2t[kb + 2][co0];
          const float wb0 = wl2t[kb + 0][co0 + 1], wb1 = wl2t[kb + 1][co0 + 1], wb2 = wl2t[kb + 2][co0 + 1];
#pragma unroll
          for (int ox = 0; ox < 7; ++ox) {
            if (2 * ox - 1 >= 0) { acc0[ox] += wa0 * xr[2 * ox - 1]; acc1[ox] += wb0 * xr[2 * ox - 1]; }
            acc0[ox] += wa1 * xr[2 * ox];
            acc1[ox] += wb1 * xr[2 * ox];
            if (2 * ox + 1 < 14) { acc0[ox] += wa2 * xr[2 * ox + 1]; acc1[ox] += wb2 * xr[2 * ox + 1]; }
          }
        }
      }
    }
    float* o0 = &y2p[(size_t)(n0 + s) * 896 + (co0 + 0) * 56 + oy * 8];
    float* o1 = &y2p[(size_t)(n0 + s) * 896 + (co0 + 1) * 56 + oy * 8];
#pragma unroll
    for (int ox = 0; ox < 7; ++ox) {
      o0[ox] = fmaxf(acc0[ox], 0.f);
      o1[ox] = fmaxf(acc1[ox], 0.f);
    }
  }
}

// ------------------------- conv3 + adaptive pool ---------------------------
__global__ __launch_bounds__(256) void k_conv3pool(
    const float* __restrict__ y2p,
    const float* __restrict__ w3, const float* __restrict__ b3,
    float* __restrict__ pooled) {
  __shared__ float y2s[8][16][7][8];
  __shared__ float wl3t[144][32];
  __shared__ float bl3[32];
  const int n0 = blockIdx.x * 8;
  const int tid = threadIdx.x;

  for (int i = tid; i < 4608; i += 256) {
    int k = i >> 5, co = i & 31;
    wl3t[k][co] = w3[co * 144 + k];
  }
  if (tid < 32) bl3[tid] = b3[tid];
#pragma unroll
  for (int s = 0; s < 8; ++s)
    if (tid < 224)
      reinterpret_cast<float4*>(&y2s[s][0][0][0])[tid] =
          reinterpret_cast<const float4*>(&y2p[(size_t)(n0 + s) * 896])[tid];
  __syncthreads();

  const int s = tid >> 5, co = tid & 31;
  float acc[49];
  {
    const float bb = bl3[co];
#pragma unroll
    for (int i = 0; i < 49; ++i) acc[i] = bb;
  }
  for (int ci = 0; ci < 16; ++ci) {
    float xr[7][7];
#pragma unroll
    for (int y = 0; y < 7; ++y) {
      const float4* rp = reinterpret_cast<const float4*>(&y2s[s][ci][y][0]);
      float4 qa = rp[0], qb = rp[1];
      xr[y][0] = qa.x; xr[y][1] = qa.y; xr[y][2] = qa.z; xr[y][3] = qa.w;
      xr[y][4] = qb.x; xr[y][5] = qb.y; xr[y][6] = qb.z;
    }
    float wreg[9];
#pragma unroll
    for (int k = 0; k < 9; ++k) wreg[k] = wl3t[ci * 9 + k][co];
#pragma unroll
    for (int ky = 0; ky < 3; ++ky)
#pragma unroll
      for (int kx = 0; kx < 3; ++kx) {
        const float w = wreg[ky * 3 + kx];
#pragma unroll
        for (int oy = 0; oy < 7; ++oy) {
          const int y = oy - 1 + ky;
          if (y >= 0 && y < 7) {
#pragma unroll
            for (int ox = 0; ox < 7; ++ox) {
              const int xx = ox - 1 + kx;
              if (xx >= 0 && xx < 7) acc[oy * 7 + ox] += w * xr[y][xx];
            }
          }
        }
      }
  }
#pragma unroll
  for (int i = 0; i < 49; ++i) acc[i] = fmaxf(acc[i], 0.f);
  float* out = pooled + (size_t)(n0 + s) * 288 + co * 9;
#pragma unroll
  for (int py = 0; py < 3; ++py)
#pragma unroll
    for (int px = 0; px < 3; ++px) {
      float v = 0.f;
#pragma unroll
      for (int dy = 0; dy < 3; ++dy)
#pragma unroll
        for (int dx = 0; dx < 3; ++dx) v += acc[(2 * py + dy) * 7 + (2 * px + dx)];
      out[py * 3 + px] = v * (1.f / 9.f);
    }
}

// ------------------- 16-row GEMM, vectorized LDS fragments -----------------
// C[16 x NT] per block, grid = M/16 = 512. A[M,K] * B[NT,K]^T. 256 threads.
// Thread (tr=tid>>5, tc=tid&31): rows tr*2+{0,1}; cols nc*128 + tc*4 + {0..3}.
// LDS: AT stride 20 (rows 8B-aligned, A-read = float2 broadcast),
//      BT stride NT+4 (rows 16B-aligned; B-read = ds_read_b128, wave sweeps
//      32 contiguous chunks x2 broadcast -> conflict-free).
// EP: 0=PLAIN(bias+relu), 1=NORM(+row L2-normalize), 2=QSUM(signed sq-sum).
// ASYNTH: A[m,k]=relu(sq[m]*sw[k]+sb[k]) synthesized during staging.
template <int NT, int EP, bool ASYNTH>
__global__ __launch_bounds__(256) void k_rowgemm16(
    const float* __restrict__ A, const float* __restrict__ Bm,
    const float* __restrict__ bias, float* __restrict__ C,
    const float* __restrict__ sq, const float* __restrict__ sw,
    const float* __restrict__ sb, int K) {
  static_assert(NT == 128 || NT == 256, "NT");
  constexpr int NC = NT / 128;
  constexpr int NB4 = NT / 32;        // float4 B-loads per thread per K-step
  constexpr int BS = NT + 4;          // BT row stride (floats): 16B-aligned, ==4 mod 32
  __shared__ float AT[32 * 20];
  __shared__ float BT[32 * BS];
  const int m0 = blockIdx.x * 16;
  const int tid = threadIdx.x;
  const int tr = tid >> 5, tc = tid & 31;

  float ra[2];
  float4 rb[NB4];

  auto loadAB = [&](int k0) {
#pragma unroll
    for (int e = 0; e < 2; ++e) {
      const int idx = tid + e * 256;
      const int mm = idx >> 5, kk = idx & 31;
      if (ASYNTH) ra[e] = fmaxf(sq[m0 + mm] * sw[k0 + kk] + sb[k0 + kk], 0.f);
      else ra[e] = A[(size_t)(m0 + mm) * K + k0 + kk];
    }
#pragma unroll
    for (int e = 0; e < NB4; ++e) {
      const int idx4 = tid + e * 256;
      const int nn = idx4 >> 3, kq = idx4 & 7;
      rb[e] = *reinterpret_cast<const float4*>(&Bm[(size_t)nn * K + k0 + kq * 4]);
    }
  };
  auto storeAB = [&]() {
#pragma unroll
    for (int e = 0; e < 2; ++e) {
      const int idx = tid + e * 256;
      AT[(idx & 31) * 20 + (idx >> 5)] = ra[e];
    }
#pragma unroll
    for (int e = 0; e < NB4; ++e) {
      const int idx4 = tid + e * 256;
      const int nn = idx4 >> 3, kq = idx4 & 7;
      BT[(kq * 4 + 0) * BS + nn] = rb[e].x;
      BT[(kq * 4 + 1) * BS + nn] = rb[e].y;
      BT[(kq * 4 + 2) * BS + nn] = rb[e].z;
      BT[(kq * 4 + 3) * BS + nn] = rb[e].w;
    }
  };

  float acc[2][NC][4];
#pragma unroll
  for (int i = 0; i < 2; ++i)
#pragma unroll
    for (int nc = 0; nc < NC; ++nc)
#pragma unroll
      for (int j = 0; j < 4; ++j) acc[i][nc][j] = 0.f;

  loadAB(0);
  for (int k0 = 0; k0 < K; k0 += 32) {
    __syncthreads();
    storeAB();
    __syncthreads();
    if (k0 + 32 < K) loadAB(k0 + 32);   // next-tile loads issue under compute
#pragma unroll
    for (int kk = 0; kk < 32; ++kk) {
      const float2 a2 = *reinterpret_cast<const float2*>(&AT[kk * 20 + tr * 2]);
#pragma unroll
      for (int nc = 0; nc < NC; ++nc) {
        const float4 b4 = *reinterpret_cast<const float4*>(
            &BT[kk * BS + nc * 128 + tc * 4]);
        acc[0][nc][0] += a2.x * b4.x; acc[0][nc][1] += a2.x * b4.y;
        acc[0][nc][2] += a2.x * b4.z; acc[0][nc][3] += a2.x * b4.w;
        acc[1][nc][0] += a2.y * b4.x; acc[1][nc][1] += a2.y * b4.y;
        acc[1][nc][2] += a2.y * b4.z; acc[1][nc][3] += a2.y * b4.w;
      }
    }
  }

  if (EP == 2) {  // QSUM -> C is qv[M]; cols<128 +, cols>=128 -
    float qp[2] = {0.f, 0.f};
#pragma unroll
    for (int i = 0; i < 2; ++i)
#pragma unroll
      for (int nc = 0; nc < NC; ++nc)
#pragma unroll
        for (int j = 0; j < 4; ++j) {
          const float v = acc[i][nc][j];
          qp[i] += (nc == 0) ? v * v : -v * v;
        }
#pragma unroll
    for (int i = 0; i < 2; ++i)
#pragma unroll
      for (int d = 1; d < 32; d <<= 1) qp[i] += __shfl_xor(qp[i], d, 64);
    if (tc == 0) {
#pragma unroll
      for (int i = 0; i < 2; ++i) C[m0 + tr * 2 + i] = qp[i];
    }
  } else if (EP == 1) {  // NORM
    float t[2][NC][4];
    float ss[2] = {0.f, 0.f};
#pragma unroll
    for (int i = 0; i < 2; ++i)
#pragma unroll
      for (int nc = 0; nc < NC; ++nc)
#pragma unroll
        for (int j = 0; j < 4; ++j) {
          const float v = fmaxf(acc[i][nc][j] + bias[nc * 128 + tc * 4 + j], 0.f);
          t[i][nc][j] = v;
          ss[i] += v * v;
        }
#pragma unroll
    for (int i = 0; i < 2; ++i)
#pragma unroll
      for (int d = 1; d < 32; d <<= 1) ss[i] += __shfl_xor(ss[i], d, 64);
#pragma unroll
    for (int i = 0; i < 2; ++i) {
      const float sc = 1.f / fmaxf(sqrtf(ss[i]), 1e-12f);
#pragma unroll
      for (int nc = 0; nc < NC; ++nc) {
        float4 v;
        v.x = t[i][nc][0] * sc; v.y = t[i][nc][1] * sc;
        v.z = t[i][nc][2] * sc; v.w = t[i][nc][3] * sc;
        *reinterpret_cast<float4*>(&C[(size_t)(m0 + tr * 2 + i) * NT + nc * 128 + tc * 4]) = v;
      }
    }
  } else {  // PLAIN
#pragma unroll
    for (int i = 0; i < 2; ++i)
#pragma unroll
      for (int nc = 0; nc < NC; ++nc) {
        float4 v;
        v.x = fmaxf(acc[i][nc][0] + bias[nc * 128 + tc * 4 + 0], 0.f);
        v.y = fmaxf(acc[i][nc][1] + bias[nc * 128 + tc * 4 + 1], 0.f);
        v.z = fmaxf(acc[i][nc][2] + bias[nc * 128 + tc * 4 + 2], 0.f);
        v.w = fmaxf(acc[i][nc][3] + bias[nc * 128 + tc * 4 + 3], 0.f);
        *reinterpret_cast<float4*>(&C[(size_t)(m0 + tr * 2 + i) * NT + nc * 128 + tc * 4]) = v;
      }
  }
}

// ------------------- 64-row GEMM (tiny c4 layer), vectorized ---------------
// Thread (tr=tid>>4, tc=tid&15): rows tr*4+{0..3}, cols tc*4+{0..3}.
// AT/BT stride 68 (16B-aligned rows) -> float4 fragment reads.
template <int NT>
__global__ __launch_bounds__(256) void k_rowgemm64(
    const float* __restrict__ A, const float* __restrict__ Bm,
    const float* __restrict__ bias, float* __restrict__ C, int K) {
  constexpr int NB = NT / 64;
  __shared__ float AT[32 * 68];
  __shared__ float BT[32 * (NT + 4)];
  constexpr int BS = NT + 4;
  const int m0 = blockIdx.x * 64;
  const int tid = threadIdx.x;
  const int tr = tid >> 4, tc = tid & 15;
  float acc[4][NB][4];
#pragma unroll
  for (int i = 0; i < 4; ++i)
#pragma unroll
    for (int nb = 0; nb < NB; ++nb)
#pragma unroll
      for (int j = 0; j < 4; ++j) acc[i][nb][j] = 0.f;

  for (int k0 = 0; k0 < K; k0 += 32) {
#pragma unroll
    for (int e = 0; e < 8; ++e) {
      int idx = tid + e * 256;
      int mm = idx >> 5, kk = idx & 31;
      AT[kk * 68 + mm] = A[(size_t)(m0 + mm) * K + k0 + kk];
    }
#pragma unroll
    for (int e = 0; e < NB * 8; ++e) {
      int idx = tid + e * 256;
      int nn = idx >> 5, kk = idx & 31;
      BT[kk * BS + nn] = Bm[(size_t)nn * K + k0 + kk];
    }
    __syncthreads();
#pragma unroll
    for (int kk = 0; kk < 32; ++kk) {
      const float4 a4 = *reinterpret_cast<const float4*>(&AT[kk * 68 + tr * 4]);
      const float a[4] = {a4.x, a4.y, a4.z, a4.w};
#pragma unroll
      for (int nb = 0; nb < NB; ++nb) {
        const float4 b4 = *reinterpret_cast<const float4*>(&BT[kk * BS + nb * 64 + tc * 4]);
        const float b[4] = {b4.x, b4.y, b4.z, b4.w};
#pragma unroll
        for (int i = 0; i < 4; ++i)
#pragma unroll
          for (int j = 0; j < 4; ++j) acc[i][nb][j] += a[i] * b[j];
      }
    }
    __syncthreads();
  }
#pragma unroll
  for (int i = 0; i < 4; ++i)
#pragma unroll
    for (int nb = 0; nb < NB; ++nb) {
      float4 v;
      v.x = fmaxf(acc[i][nb][0] + bias[nb * 64 + tc * 4 + 0], 0.f);
      v.y = fmaxf(acc[i][nb][1] + bias[nb * 64 + tc * 4 + 1], 0.f);
      v.z = fmaxf(acc[i][nb][2] + bias[nb * 64 + tc * 4 + 2], 0.f);
      v.w = fmaxf(acc[i][nb][3] + bias[nb * 64 + tc * 4 + 3], 0.f);
      *reinterpret_cast<float4*>(&C[(size_t)(m0 + tr * 4 + i) * NT + nb * 64 + tc * 4]) = v;
    }
}

// ------------------------- quantum circuit -> U ----------------------------
__global__ __launch_bounds__(64) void k_buildU(const float* __restrict__ qw,
                                               float* __restrict__ Uw) {
  const int j = blockIdx.x;
  const int t = threadIdx.x;
  float a0 = (t == j) ? 1.f : 0.f;
  float a1 = (64 + t == j) ? 1.f : 0.f;
  float a2 = (128 + t == j) ? 1.f : 0.f;
  float a3 = (192 + t == j) ? 1.f : 0.f;
  for (int l = 0; l < 7; ++l) {
#pragma unroll
    for (int q = 0; q < 8; ++q) {
      const float th = 0.5f * qw[l * 8 + q];
      const float c = cosf(th), s = sinf(th);
      const int m = 7 - q;
      if (m == 7) {
        const float n0 = c * a0 - s * a2, n2 = s * a0 + c * a2;
        const float n1 = c * a1 - s * a3, n3 = s * a1 + c * a3;
        a0 = n0; a2 = n2; a1 = n1; a3 = n3;
      } else if (m == 6) {
        const float n0 = c * a0 - s * a1, n1 = s * a0 + c * a1;
        const float n2 = c * a2 - s * a3, n3 = s * a2 + c * a3;
        a0 = n0; a1 = n1; a2 = n2; a3 = n3;
      } else {
        const float p0 = __shfl_xor(a0, 1 << m, 64);
        const float p1 = __shfl_xor(a1, 1 << m, 64);
        const float p2 = __shfl_xor(a2, 1 << m, 64);
        const float p3 = __shfl_xor(a3, 1 << m, 64);
        const float sgn = ((t >> m) & 1) ? s : -s;
        a0 = c * a0 + sgn * p0; a1 = c * a1 + sgn * p1;
        a2 = c * a2 + sgn * p2; a3 = c * a3 + sgn * p3;
      }
    }
#pragma unroll
    for (int q = 0; q < 7; ++q) {
      const int mc = 7 - q, mt = mc - 1;
      if (mc == 7) {
        const float tmp = a2; a2 = a3; a3 = tmp;
      } else if (mc == 6) {
        a1 = __shfl_xor(a1, 32, 64);
        a3 = __shfl_xor(a3, 32, 64);
      } else {
        const float p0 = __shfl_xor(a0, 1 << mt, 64);
        const float p1 = __shfl_xor(a1, 1 << mt, 64);
        const float p2 = __shfl_xor(a2, 1 << mt, 64);
        const float p3 = __shfl_xor(a3, 1 << mt, 64);
        if ((t >> mc) & 1) { a0 = p0; a1 = p1; a2 = p2; a3 = p3; }
      }
    }
  }
  Uw[(0 * 64 + t) * 256 + j] = a0;
  Uw[(1 * 64 + t) * 256 + j] = a1;
  Uw[(2 * 64 + t) * 256 + j] = a2;
  Uw[(3 * 64 + t) * 256 + j] = a3;
}

// ------------------------- final layer -------------------------------------
__global__ __launch_bounds__(256) void k_head5(const float* __restrict__ h4,
                                               const float* __restrict__ w,
                                               const float* __restrict__ b,
                                               float* __restrict__ out) {
  const int row = blockIdx.x * 4 + (threadIdx.x >> 6);
  const int lane = threadIdx.x & 63;
  float s = h4[(size_t)row * 64 + lane] * w[lane];
#pragma unroll
  for (int d = 32; d > 0; d >>= 1) s += __shfl_xor(s, d, 64);
  if (lane == 0) out[row] = 1.f / (1.f + expf(-(s + b[0])));
}

// ---------------------------------------------------------------------------
extern "C" void kernel_launch(void* const* d_in, const int* in_sizes, int n_in,
                              void* d_out, int out_size, void* d_ws, size_t ws_size,
                              hipStream_t stream) {
  const float* x       = (const float*)d_in[0];
  const float* conv1_w = (const float*)d_in[1];
  const float* conv1_b = (const float*)d_in[2];
  const float* conv2_w = (const float*)d_in[3];
  const float* conv2_b = (const float*)d_in[4];
  const float* conv3_w = (const float*)d_in[5];
  const float* conv3_b = (const float*)d_in[6];
  const float* fc_w    = (const float*)d_in[7];
  const float* fc_b    = (const float*)d_in[8];
  const float* q_w     = (const float*)d_in[9];
  const float* c1_w    = (const float*)d_in[10];
  const float* c1_b    = (const float*)d_in[11];
  const float* c2_w    = (const float*)d_in[12];
  const float* c2_b    = (const float*)d_in[13];
  const float* c3_w    = (const float*)d_in[14];
  const float* c3_b    = (const float*)d_in[15];
  const float* c4_w    = (const float*)d_in[16];
  const float* c4_b    = (const float*)d_in[17];
  const float* c5_w    = (const float*)d_in[18];
  const float* c5_b    = (const float*)d_in[19];
  float* out = (float*)d_out;
  char* ws = (char*)d_ws;

  // workspace layout (peak 38.8 MB): y2p region recycled after conv3pool.
  float* y2p    = (float*)(ws + 0);          // 8192*896*4 = 29,360,128
  float* pooled = (float*)(ws + 29360128);   // 8192*288*4 =  9,437,184
  float* feat   = (float*)(ws + 0);          // 8192*256*4 =  8,388,608 (y2p dead)
  float* Uw     = (float*)(ws + 8388608);    // 256*256*4  =    262,144
  float* qv     = (float*)(ws + 8650752);    // 8192*4     =     32,768
  float* h2     = (float*)(ws + 8683520);    // 8192*256*4 =  8,388,608
  float* h3     = (float*)(ws + 17072128);   // 8192*128*4 =  4,194,304
  float* h4     = (float*)(ws + 21266432);   // 8192*64*4  =  2,097,152
  (void)in_sizes; (void)n_in; (void)out_size; (void)ws_size;

  k_conv12<<<2048, 256, 0, stream>>>(x, conv1_w, conv1_b, conv2_w, conv2_b, y2p);
  k_conv3pool<<<1024, 256, 0, stream>>>(y2p, conv3_w, conv3_b, pooled);
  // fc (K=288) + relu + L2-normalize rows -> feat
  k_rowgemm16<256, 1, false><<<512, 256, 0, stream>>>(pooled, fc_w, fc_b, feat,
                                                      nullptr, nullptr, nullptr, 288);
  k_buildU<<<256, 64, 0, stream>>>(q_w, Uw);
  // phi = feat @ U^T fused with q = sum_{n<128} phi^2 - sum_{n>=128} phi^2
  k_rowgemm16<256, 2, false><<<512, 256, 0, stream>>>(feat, Uw, nullptr, qv,
                                                      nullptr, nullptr, nullptr, 256);
  // h2 = relu( relu(q*c1w+c1b) @ c2^T + c2b )  (h1 synthesized, K=512)
  k_rowgemm16<256, 0, true><<<512, 256, 0, stream>>>(nullptr, c2_w, c2_b, h2,
                                                     qv, c1_w, c1_b, 512);
  // h3 = relu(h2 @ c3^T + c3b)  (K=256, N=128)
  k_rowgemm16<128, 0, false><<<512, 256, 0, stream>>>(h2, c3_w, c3_b, h3,
                                                      nullptr, nullptr, nullptr, 256);
  // h4 = relu(h3 @ c4^T + c4b)  (K=128, N=64)
  k_rowgemm64<64><<<128, 256, 0, stream>>>(h3, c4_w, c4_b, h4, 128);
  k_head5<<<2048, 256, 0, stream>>>(h4, c5_w, c5_b, out);
}

// Round 7
// 350.226 us; speedup vs baseline: 1.8911x; 1.0468x over previous
//
#include <hip/hip_runtime.h>
#include <math.h>

// ---------------------------------------------------------------------------
// Precise45K CNN+QNN forward, fp32.
//  k_conv12    : conv1+conv2 fused in LDS (4 samples/blk) -> y2p [n][16][7][8]
//                y1p rows padded 16->20 floats (co-stride 280==24 mod 32,
//                oy-step 40==8 mod 32) -> bank-conflict-free stores/reads.
//  k_conv3pool : conv3 + adaptive pool, 8 samples/blk
//  k_rowgemm16 : 16-row x full-N GEMM, register-prefetch staging, vectorized
//                LDS fragment reads (stride NT+4). EP: PLAIN / NORM / QSUM;
//                ASYNTH synthesizes A[m,k]=relu(q[m]*w[k]+b[k]).
//  k_rowgemm64 : 64-row variant for tiny c4 layer
//  k_buildU    : quantum circuit -> U, single wave, shuffle-only
//  k_head5     : final dot(64) + sigmoid
// ---------------------------------------------------------------------------

// ------------------------- conv1 + conv2 -----------------------------------
__global__ __launch_bounds__(256) void k_conv12(
    const float* __restrict__ x,
    const float* __restrict__ w1, const float* __restrict__ b1,
    const float* __restrict__ w2, const float* __restrict__ b2,
    float* __restrict__ y2p) {
  __shared__ float xin[4][784];
  __shared__ float y1p[4][8][14][20];    // row padded 16->20: kills 8-way store
                                         // + 7-way read conflicts (strides
                                         // 280==24, 40==8 mod 32; rows 16B-al)
  __shared__ float wl1[200], bl1[8];
  __shared__ float wl2t[72][16], bl2[16];
  const int n0 = blockIdx.x * 4;
  const int tid = threadIdx.x;

  for (int i = tid; i < 200; i += 256) wl1[i] = w1[i];
  if (tid < 8) bl1[tid] = b1[tid];
  for (int i = tid; i < 1152; i += 256) {
    int k = i >> 4, co = i & 15;
    wl2t[k][co] = w2[co * 72 + k];
  }
  if (tid < 16) bl2[tid] = b2[tid];
#pragma unroll
  for (int s = 0; s < 4; ++s)
    if (tid < 196)
      reinterpret_cast<float4*>(&xin[s][0])[tid] =
          reinterpret_cast<const float4*>(&x[(size_t)(n0 + s) * 784])[tid];
  __syncthreads();

  if (tid < 224) {
    const int s = tid / 56, r = tid % 56, co = r / 7, oyh = r % 7;
    float wreg[25];
#pragma unroll
    for (int i = 0; i < 25; ++i) wreg[i] = wl1[co * 25 + i];
    const float bb = bl1[co];
#pragma unroll
    for (int half = 0; half < 2; ++half) {
      const int oy = oyh + half * 7;
      float acc[14];
#pragma unroll
      for (int ox = 0; ox < 14; ++ox) acc[ox] = bb;
#pragma unroll
      for (int ky = 0; ky < 5; ++ky) {
        const int y = oy * 2 - 2 + ky;
        if (y >= 0 && y < 28) {
          const float4* xp = reinterpret_cast<const float4*>(&xin[s][y * 28]);
          float xr[28];
#pragma unroll
          for (int v = 0; v < 7; ++v) {
            float4 q = xp[v];
            xr[v * 4 + 0] = q.x; xr[v * 4 + 1] = q.y;
            xr[v * 4 + 2] = q.z; xr[v * 4 + 3] = q.w;
          }
#pragma unroll
          for (int kx = 0; kx < 5; ++kx) {
            const float w = wreg[ky * 5 + kx];
#pragma unroll
            for (int ox = 0; ox < 14; ++ox) {
              const int xx = ox * 2 - 2 + kx;
              if (xx >= 0 && xx < 28) acc[ox] += w * xr[xx];
            }
          }
        }
      }
#pragma unroll
      for (int ox = 0; ox < 14; ++ox) y1p[s][co][oy][ox] = fmaxf(acc[ox], 0.f);
    }
  }
  __syncthreads();

  if (tid < 224) {
    const int s = tid / 56, r = tid % 56, cop = r / 7, oy = r % 7;
    const int co0 = cop * 2;
    float acc0[7], acc1[7];
#pragma unroll
    for (int ox = 0; ox < 7; ++ox) { acc0[ox] = bl2[co0]; acc1[ox] = bl2[co0 + 1]; }
    for (int ci = 0; ci < 8; ++ci) {
#pragma unroll
      for (int ky = 0; ky < 3; ++ky) {
        const int y = oy * 2 - 1 + ky;
        if (y >= 0 && y < 14) {
          const float4* rp = reinterpret_cast<const float4*>(&y1p[s][ci][y][0]);
          float4 q0 = rp[0], q1 = rp[1], q2 = rp[2], q3 = rp[3];
          float xr[14] = {q0.x, q0.y, q0.z, q0.w, q1.x, q1.y, q1.z, q1.w,
                          q2.x, q2.y, q2.z, q2.w, q3.x, q3.y};
          const int kb = ci * 9 + ky * 3;
          const float wa0 = wl2t[kb + 0][co0],     wa1 = wl2t[kb + 1][co0],     wa2 = wl2t[kb + 2][co0];
          const float wb0 = wl2t[kb + 0][co0 + 1], wb1 = wl2t[kb + 1][co0 + 1], wb2 = wl2t[kb + 2][co0 + 1];
#pragma unroll
          for (int ox = 0; ox < 7; ++ox) {
            if (2 * ox - 1 >= 0) { acc0[ox] += wa0 * xr[2 * ox - 1]; acc1[ox] += wb0 * xr[2 * ox - 1]; }
            acc0[ox] += wa1 * xr[2 * ox];
            acc1[ox] += wb1 * xr[2 * ox];
            if (2 * ox + 1 < 14) { acc0[ox] += wa2 * xr[2 * ox + 1]; acc1[ox] += wb2 * xr[2 * ox + 1]; }
          }
        }
      }
    }
    float* o0 = &y2p[(size_t)(n0 + s) * 896 + (co0 + 0) * 56 + oy * 8];
    float* o1 = &y2p[(size_t)(n0 + s) * 896 + (co0 + 1) * 56 + oy * 8];
#pragma unroll
    for (int ox = 0; ox < 7; ++ox) {
      o0[ox] = fmaxf(acc0[ox], 0.f);
      o1[ox] = fmaxf(acc1[ox], 0.f);
    }
  }
}

// ------------------------- conv3 + adaptive pool ---------------------------
__global__ __launch_bounds__(256) void k_conv3pool(
    const float* __restrict__ y2p,
    const float* __restrict__ w3, const float* __restrict__ b3,
    float* __restrict__ pooled) {
  __shared__ float y2s[8][16][7][8];
  __shared__ float wl3t[144][32];
  __shared__ float bl3[32];
  const int n0 = blockIdx.x * 8;
  const int tid = threadIdx.x;

  for (int i = tid; i < 4608; i += 256) {
    int k = i >> 5, co = i & 31;
    wl3t[k][co] = w3[co * 144 + k];
  }
  if (tid < 32) bl3[tid] = b3[tid];
#pragma unroll
  for (int s = 0; s < 8; ++s)
    if (tid < 224)
      reinterpret_cast<float4*>(&y2s[s][0][0][0])[tid] =
          reinterpret_cast<const float4*>(&y2p[(size_t)(n0 + s) * 896])[tid];
  __syncthreads();

  const int s = tid >> 5, co = tid & 31;
  float acc[49];
  {
    const float bb = bl3[co];
#pragma unroll
    for (int i = 0; i < 49; ++i) acc[i] = bb;
  }
  for (int ci = 0; ci < 16; ++ci) {
    float xr[7][7];
#pragma unroll
    for (int y = 0; y < 7; ++y) {
      const float4* rp = reinterpret_cast<const float4*>(&y2s[s][ci][y][0]);
      float4 qa = rp[0], qb = rp[1];
      xr[y][0] = qa.x; xr[y][1] = qa.y; xr[y][2] = qa.z; xr[y][3] = qa.w;
      xr[y][4] = qb.x; xr[y][5] = qb.y; xr[y][6] = qb.z;
    }
    float wreg[9];
#pragma unroll
    for (int k = 0; k < 9; ++k) wreg[k] = wl3t[ci * 9 + k][co];
#pragma unroll
    for (int ky = 0; ky < 3; ++ky)
#pragma unroll
      for (int kx = 0; kx < 3; ++kx) {
        const float w = wreg[ky * 3 + kx];
#pragma unroll
        for (int oy = 0; oy < 7; ++oy) {
          const int y = oy - 1 + ky;
          if (y >= 0 && y < 7) {
#pragma unroll
            for (int ox = 0; ox < 7; ++ox) {
              const int xx = ox - 1 + kx;
              if (xx >= 0 && xx < 7) acc[oy * 7 + ox] += w * xr[y][xx];
            }
          }
        }
      }
  }
#pragma unroll
  for (int i = 0; i < 49; ++i) acc[i] = fmaxf(acc[i], 0.f);
  float* out = pooled + (size_t)(n0 + s) * 288 + co * 9;
#pragma unroll
  for (int py = 0; py < 3; ++py)
#pragma unroll
    for (int px = 0; px < 3; ++px) {
      float v = 0.f;
#pragma unroll
      for (int dy = 0; dy < 3; ++dy)
#pragma unroll
        for (int dx = 0; dx < 3; ++dx) v += acc[(2 * py + dy) * 7 + (2 * px + dx)];
      out[py * 3 + px] = v * (1.f / 9.f);
    }
}

// ------------------- 16-row GEMM, vectorized LDS fragments -----------------
// C[16 x NT] per block, grid = M/16 = 512. A[M,K] * B[NT,K]^T. 256 threads.
// Thread (tr=tid>>5, tc=tid&31): rows tr*2+{0,1}; cols nc*128 + tc*4 + {0..3}.
// LDS: AT stride 20 (rows 8B-aligned, A-read = float2 broadcast),
//      BT stride NT+4 (rows 16B-aligned; B-read = ds_read_b128, conflict-free).
// EP: 0=PLAIN(bias+relu), 1=NORM(+row L2-normalize), 2=QSUM(signed sq-sum).
// ASYNTH: A[m,k]=relu(sq[m]*sw[k]+sb[k]) synthesized during staging.
template <int NT, int EP, bool ASYNTH>
__global__ __launch_bounds__(256) void k_rowgemm16(
    const float* __restrict__ A, const float* __restrict__ Bm,
    const float* __restrict__ bias, float* __restrict__ C,
    const float* __restrict__ sq, const float* __restrict__ sw,
    const float* __restrict__ sb, int K) {
  static_assert(NT == 128 || NT == 256, "NT");
  constexpr int NC = NT / 128;
  constexpr int NB4 = NT / 32;        // float4 B-loads per thread per K-step
  constexpr int BS = NT + 4;          // BT row stride (floats): 16B-aligned, ==4 mod 32
  __shared__ float AT[32 * 20];
  __shared__ float BT[32 * BS];
  const int m0 = blockIdx.x * 16;
  const int tid = threadIdx.x;
  const int tr = tid >> 5, tc = tid & 31;

  float ra[2];
  float4 rb[NB4];

  auto loadAB = [&](int k0) {
#pragma unroll
    for (int e = 0; e < 2; ++e) {
      const int idx = tid + e * 256;
      const int mm = idx >> 5, kk = idx & 31;
      if (ASYNTH) ra[e] = fmaxf(sq[m0 + mm] * sw[k0 + kk] + sb[k0 + kk], 0.f);
      else ra[e] = A[(size_t)(m0 + mm) * K + k0 + kk];
    }
#pragma unroll
    for (int e = 0; e < NB4; ++e) {
      const int idx4 = tid + e * 256;
      const int nn = idx4 >> 3, kq = idx4 & 7;
      rb[e] = *reinterpret_cast<const float4*>(&Bm[(size_t)nn * K + k0 + kq * 4]);
    }
  };
  auto storeAB = [&]() {
#pragma unroll
    for (int e = 0; e < 2; ++e) {
      const int idx = tid + e * 256;
      AT[(idx & 31) * 20 + (idx >> 5)] = ra[e];
    }
#pragma unroll
    for (int e = 0; e < NB4; ++e) {
      const int idx4 = tid + e * 256;
      const int nn = idx4 >> 3, kq = idx4 & 7;
      BT[(kq * 4 + 0) * BS + nn] = rb[e].x;
      BT[(kq * 4 + 1) * BS + nn] = rb[e].y;
      BT[(kq * 4 + 2) * BS + nn] = rb[e].z;
      BT[(kq * 4 + 3) * BS + nn] = rb[e].w;
    }
  };

  float acc[2][NC][4];
#pragma unroll
  for (int i = 0; i < 2; ++i)
#pragma unroll
    for (int nc = 0; nc < NC; ++nc)
#pragma unroll
      for (int j = 0; j < 4; ++j) acc[i][nc][j] = 0.f;

  loadAB(0);
  for (int k0 = 0; k0 < K; k0 += 32) {
    __syncthreads();
    storeAB();
    __syncthreads();
    if (k0 + 32 < K) loadAB(k0 + 32);   // next-tile loads issue under compute
#pragma unroll
    for (int kk = 0; kk < 32; ++kk) {
      const float2 a2 = *reinterpret_cast<const float2*>(&AT[kk * 20 + tr * 2]);
#pragma unroll
      for (int nc = 0; nc < NC; ++nc) {
        const float4 b4 = *reinterpret_cast<const float4*>(
            &BT[kk * BS + nc * 128 + tc * 4]);
        acc[0][nc][0] += a2.x * b4.x; acc[0][nc][1] += a2.x * b4.y;
        acc[0][nc][2] += a2.x * b4.z; acc[0][nc][3] += a2.x * b4.w;
        acc[1][nc][0] += a2.y * b4.x; acc[1][nc][1] += a2.y * b4.y;
        acc[1][nc][2] += a2.y * b4.z; acc[1][nc][3] += a2.y * b4.w;
      }
    }
  }

  if (EP == 2) {  // QSUM -> C is qv[M]; cols<128 +, cols>=128 -
    float qp[2] = {0.f, 0.f};
#pragma unroll
    for (int i = 0; i < 2; ++i)
#pragma unroll
      for (int nc = 0; nc < NC; ++nc)
#pragma unroll
        for (int j = 0; j < 4; ++j) {
          const float v = acc[i][nc][j];
          qp[i] += (nc == 0) ? v * v : -v * v;
        }
#pragma unroll
    for (int i = 0; i < 2; ++i)
#pragma unroll
      for (int d = 1; d < 32; d <<= 1) qp[i] += __shfl_xor(qp[i], d, 64);
    if (tc == 0) {
#pragma unroll
      for (int i = 0; i < 2; ++i) C[m0 + tr * 2 + i] = qp[i];
    }
  } else if (EP == 1) {  // NORM
    float t[2][NC][4];
    float ss[2] = {0.f, 0.f};
#pragma unroll
    for (int i = 0; i < 2; ++i)
#pragma unroll
      for (int nc = 0; nc < NC; ++nc)
#pragma unroll
        for (int j = 0; j < 4; ++j) {
          const float v = fmaxf(acc[i][nc][j] + bias[nc * 128 + tc * 4 + j], 0.f);
          t[i][nc][j] = v;
          ss[i] += v * v;
        }
#pragma unroll
    for (int i = 0; i < 2; ++i)
#pragma unroll
      for (int d = 1; d < 32; d <<= 1) ss[i] += __shfl_xor(ss[i], d, 64);
#pragma unroll
    for (int i = 0; i < 2; ++i) {
      const float sc = 1.f / fmaxf(sqrtf(ss[i]), 1e-12f);
#pragma unroll
      for (int nc = 0; nc < NC; ++nc) {
        float4 v;
        v.x = t[i][nc][0] * sc; v.y = t[i][nc][1] * sc;
        v.z = t[i][nc][2] * sc; v.w = t[i][nc][3] * sc;
        *reinterpret_cast<float4*>(&C[(size_t)(m0 + tr * 2 + i) * NT + nc * 128 + tc * 4]) = v;
      }
    }
  } else {  // PLAIN
#pragma unroll
    for (int i = 0; i < 2; ++i)
#pragma unroll
      for (int nc = 0; nc < NC; ++nc) {
        float4 v;
        v.x = fmaxf(acc[i][nc][0] + bias[nc * 128 + tc * 4 + 0], 0.f);
        v.y = fmaxf(acc[i][nc][1] + bias[nc * 128 + tc * 4 + 1], 0.f);
        v.z = fmaxf(acc[i][nc][2] + bias[nc * 128 + tc * 4 + 2], 0.f);
        v.w = fmaxf(acc[i][nc][3] + bias[nc * 128 + tc * 4 + 3], 0.f);
        *reinterpret_cast<float4*>(&C[(size_t)(m0 + tr * 2 + i) * NT + nc * 128 + tc * 4]) = v;
      }
  }
}

// ------------------- 64-row GEMM (tiny c4 layer), vectorized ---------------
template <int NT>
__global__ __launch_bounds__(256) void k_rowgemm64(
    const float* __restrict__ A, const float* __restrict__ Bm,
    const float* __restrict__ bias, float* __restrict__ C, int K) {
  constexpr int NB = NT / 64;
  __shared__ float AT[32 * 68];
  __shared__ float BT[32 * (NT + 4)];
  constexpr int BS = NT + 4;
  const int m0 = blockIdx.x * 64;
  const int tid = threadIdx.x;
  const int tr = tid >> 4, tc = tid & 15;
  float acc[4][NB][4];
#pragma unroll
  for (int i = 0; i < 4; ++i)
#pragma unroll
    for (int nb = 0; nb < NB; ++nb)
#pragma unroll
      for (int j = 0; j < 4; ++j) acc[i][nb][j] = 0.f;

  for (int k0 = 0; k0 < K; k0 += 32) {
#pragma unroll
    for (int e = 0; e < 8; ++e) {
      int idx = tid + e * 256;
      int mm = idx >> 5, kk = idx & 31;
      AT[kk * 68 + mm] = A[(size_t)(m0 + mm) * K + k0 + kk];
    }
#pragma unroll
    for (int e = 0; e < NB * 8; ++e) {
      int idx = tid + e * 256;
      int nn = idx >> 5, kk = idx & 31;
      BT[kk * BS + nn] = Bm[(size_t)nn * K + k0 + kk];
    }
    __syncthreads();
#pragma unroll
    for (int kk = 0; kk < 32; ++kk) {
      const float4 a4 = *reinterpret_cast<const float4*>(&AT[kk * 68 + tr * 4]);
      const float a[4] = {a4.x, a4.y, a4.z, a4.w};
#pragma unroll
      for (int nb = 0; nb < NB; ++nb) {
        const float4 b4 = *reinterpret_cast<const float4*>(&BT[kk * BS + nb * 64 + tc * 4]);
        const float b[4] = {b4.x, b4.y, b4.z, b4.w};
#pragma unroll
        for (int i = 0; i < 4; ++i)
#pragma unroll
          for (int j = 0; j < 4; ++j) acc[i][nb][j] += a[i] * b[j];
      }
    }
    __syncthreads();
  }
#pragma unroll
  for (int i = 0; i < 4; ++i)
#pragma unroll
    for (int nb = 0; nb < NB; ++nb) {
      float4 v;
      v.x = fmaxf(acc[i][nb][0] + bias[nb * 64 + tc * 4 + 0], 0.f);
      v.y = fmaxf(acc[i][nb][1] + bias[nb * 64 + tc * 4 + 1], 0.f);
      v.z = fmaxf(acc[i][nb][2] + bias[nb * 64 + tc * 4 + 2], 0.f);
      v.w = fmaxf(acc[i][nb][3] + bias[nb * 64 + tc * 4 + 3], 0.f);
      *reinterpret_cast<float4*>(&C[(size_t)(m0 + tr * 4 + i) * NT + nb * 64 + tc * 4]) = v;
    }
}

// ------------------------- quantum circuit -> U ----------------------------
__global__ __launch_bounds__(64) void k_buildU(const float* __restrict__ qw,
                                               float* __restrict__ Uw) {
  const int j = blockIdx.x;
  const int t = threadIdx.x;
  float a0 = (t == j) ? 1.f : 0.f;
  float a1 = (64 + t == j) ? 1.f : 0.f;
  float a2 = (128 + t == j) ? 1.f : 0.f;
  float a3 = (192 + t == j) ? 1.f : 0.f;
  for (int l = 0; l < 7; ++l) {
#pragma unroll
    for (int q = 0; q < 8; ++q) {
      const float th = 0.5f * qw[l * 8 + q];
      const float c = cosf(th), s = sinf(th);
      const int m = 7 - q;
      if (m == 7) {
        const float n0 = c * a0 - s * a2, n2 = s * a0 + c * a2;
        const float n1 = c * a1 - s * a3, n3 = s * a1 + c * a3;
        a0 = n0; a2 = n2; a1 = n1; a3 = n3;
      } else if (m == 6) {
        const float n0 = c * a0 - s * a1, n1 = s * a0 + c * a1;
        const float n2 = c * a2 - s * a3, n3 = s * a2 + c * a3;
        a0 = n0; a1 = n1; a2 = n2; a3 = n3;
      } else {
        const float p0 = __shfl_xor(a0, 1 << m, 64);
        const float p1 = __shfl_xor(a1, 1 << m, 64);
        const float p2 = __shfl_xor(a2, 1 << m, 64);
        const float p3 = __shfl_xor(a3, 1 << m, 64);
        const float sgn = ((t >> m) & 1) ? s : -s;
        a0 = c * a0 + sgn * p0; a1 = c * a1 + sgn * p1;
        a2 = c * a2 + sgn * p2; a3 = c * a3 + sgn * p3;
      }
    }
#pragma unroll
    for (int q = 0; q < 7; ++q) {
      const int mc = 7 - q, mt = mc - 1;
      if (mc == 7) {
        const float tmp = a2; a2 = a3; a3 = tmp;
      } else if (mc == 6) {
        a1 = __shfl_xor(a1, 32, 64);
        a3 = __shfl_xor(a3, 32, 64);
      } else {
        const float p0 = __shfl_xor(a0, 1 << mt, 64);
        const float p1 = __shfl_xor(a1, 1 << mt, 64);
        const float p2 = __shfl_xor(a2, 1 << mt, 64);
        const float p3 = __shfl_xor(a3, 1 << mt, 64);
        if ((t >> mc) & 1) { a0 = p0; a1 = p1; a2 = p2; a3 = p3; }
      }
    }
  }
  Uw[(0 * 64 + t) * 256 + j] = a0;
  Uw[(1 * 64 + t) * 256 + j] = a1;
  Uw[(2 * 64 + t) * 256 + j] = a2;
  Uw[(3 * 64 + t) * 256 + j] = a3;
}

// ------------------------- final layer -------------------------------------
__global__ __launch_bounds__(256) void k_head5(const float* __restrict__ h4,
                                               const float* __restrict__ w,
                                               const float* __restrict__ b,
                                               float* __restrict__ out) {
  const int row = blockIdx.x * 4 + (threadIdx.x >> 6);
  const int lane = threadIdx.x & 63;
  float s = h4[(size_t)row * 64 + lane] * w[lane];
#pragma unroll
  for (int d = 32; d > 0; d >>= 1) s += __shfl_xor(s, d, 64);
  if (lane == 0) out[row] = 1.f / (1.f + expf(-(s + b[0])));
}

// ---------------------------------------------------------------------------
extern "C" void kernel_launch(void* const* d_in, const int* in_sizes, int n_in,
                              void* d_out, int out_size, void* d_ws, size_t ws_size,
                              hipStream_t stream) {
  const float* x       = (const float*)d_in[0];
  const float* conv1_w = (const float*)d_in[1];
  const float* conv1_b = (const float*)d_in[2];
  const float* conv2_w = (const float*)d_in[3];
  const float* conv2_b = (const float*)d_in[4];
  const float* conv3_w = (const float*)d_in[5];
  const float* conv3_b = (const float*)d_in[6];
  const float* fc_w    = (const float*)d_in[7];
  const float* fc_b    = (const float*)d_in[8];
  const float* q_w     = (const float*)d_in[9];
  const float* c1_w    = (const float*)d_in[10];
  const float* c1_b    = (const float*)d_in[11];
  const float* c2_w    = (const float*)d_in[12];
  const float* c2_b    = (const float*)d_in[13];
  const float* c3_w    = (const float*)d_in[14];
  const float* c3_b    = (const float*)d_in[15];
  const float* c4_w    = (const float*)d_in[16];
  const float* c4_b    = (const float*)d_in[17];
  const float* c5_w    = (const float*)d_in[18];
  const float* c5_b    = (const float*)d_in[19];
  float* out = (float*)d_out;
  char* ws = (char*)d_ws;

  // workspace layout (peak 38.8 MB): y2p region recycled after conv3pool.
  float* y2p    = (float*)(ws + 0);          // 8192*896*4 = 29,360,128
  float* pooled = (float*)(ws + 29360128);   // 8192*288*4 =  9,437,184
  float* feat   = (float*)(ws + 0);          // 8192*256*4 =  8,388,608 (y2p dead)
  float* Uw     = (float*)(ws + 8388608);    // 256*256*4  =    262,144
  float* qv     = (float*)(ws + 8650752);    // 8192*4     =     32,768
  float* h2     = (float*)(ws + 8683520);    // 8192*256*4 =  8,388,608
  float* h3     = (float*)(ws + 17072128);   // 8192*128*4 =  4,194,304
  float* h4     = (float*)(ws + 21266432);   // 8192*64*4  =  2,097,152
  (void)in_sizes; (void)n_in; (void)out_size; (void)ws_size;

  k_conv12<<<2048, 256, 0, stream>>>(x, conv1_w, conv1_b, conv2_w, conv2_b, y2p);
  k_conv3pool<<<1024, 256, 0, stream>>>(y2p, conv3_w, conv3_b, pooled);
  // fc (K=288) + relu + L2-normalize rows -> feat
  k_rowgemm16<256, 1, false><<<512, 256, 0, stream>>>(pooled, fc_w, fc_b, feat,
                                                      nullptr, nullptr, nullptr, 288);
  k_buildU<<<256, 64, 0, stream>>>(q_w, Uw);
  // phi = feat @ U^T fused with q = sum_{n<128} phi^2 - sum_{n>=128} phi^2
  k_rowgemm16<256, 2, false><<<512, 256, 0, stream>>>(feat, Uw, nullptr, qv,
                                                      nullptr, nullptr, nullptr, 256);
  // h2 = relu( relu(q*c1w+c1b) @ c2^T + c2b )  (h1 synthesized, K=512)
  k_rowgemm16<256, 0, true><<<512, 256, 0, stream>>>(nullptr, c2_w, c2_b, h2,
                                                     qv, c1_w, c1_b, 512);
  // h3 = relu(h2 @ c3^T + c3b)  (K=256, N=128)
  k_rowgemm16<128, 0, false><<<512, 256, 0, stream>>>(h2, c3_w, c3_b, h3,
                                                      nullptr, nullptr, nullptr, 256);
  // h4 = relu(h3 @ c4^T + c4b)  (K=128, N=64)
  k_rowgemm64<64><<<128, 256, 0, stream>>>(h3, c4_w, c4_b, h4, 128);
  k_head5<<<2048, 256, 0, stream>>>(h4, c5_w, c5_b, out);
}

// Round 8
// 328.554 us; speedup vs baseline: 2.0158x; 1.0660x over previous
//
#include <hip/hip_runtime.h>
#include <math.h>

// ---------------------------------------------------------------------------
// Precise45K CNN+QNN forward.
//  k_conv12    : conv1+conv2 fused in LDS (4 samples/blk)   [fp32, validated]
//  k_conv3pool : conv3 + adaptive pool                      [fp32, validated]
//  k_rowgemm16 : fp32 GEMM for fc(NORM) and c3              [validated]
//  k_rowgemm64 : fp32 GEMM for tiny c4                      [validated]
//  k_buildU    : quantum circuit -> U, emits bf16 hi/lo splits
//  k_splitW    : fp32 weights -> bf16 hi/lo splits (c2_w)
//  k_mfma16    : NEW split-bf16 MFMA GEMM, LDS-free, for qsum and c2.
//                D = Ah*Bh + Ah*Bl + Al*Bh, fp32 accum (err ~2^-18 rel).
//  k_head5     : final dot(64) + sigmoid
// ---------------------------------------------------------------------------

typedef __attribute__((ext_vector_type(8))) short bf16x8;
typedef __attribute__((ext_vector_type(4))) float f32x4;

__device__ __forceinline__ unsigned rne_bf16(float x) {   // RNE-rounded bf16, as fp32 bits
  unsigned u = __float_as_uint(x);
  return (u + 0x7FFFu + ((u >> 16) & 1u)) & 0xFFFF0000u;
}

// ------------------------- conv1 + conv2 -----------------------------------
__global__ __launch_bounds__(256) void k_conv12(
    const float* __restrict__ x,
    const float* __restrict__ w1, const float* __restrict__ b1,
    const float* __restrict__ w2, const float* __restrict__ b2,
    float* __restrict__ y2p) {
  __shared__ float xin[4][784];
  __shared__ float y1p[4][8][14][20];
  __shared__ float wl1[200], bl1[8];
  __shared__ float wl2t[72][16], bl2[16];
  const int n0 = blockIdx.x * 4;
  const int tid = threadIdx.x;

  for (int i = tid; i < 200; i += 256) wl1[i] = w1[i];
  if (tid < 8) bl1[tid] = b1[tid];
  for (int i = tid; i < 1152; i += 256) {
    int k = i >> 4, co = i & 15;
    wl2t[k][co] = w2[co * 72 + k];
  }
  if (tid < 16) bl2[tid] = b2[tid];
#pragma unroll
  for (int s = 0; s < 4; ++s)
    if (tid < 196)
      reinterpret_cast<float4*>(&xin[s][0])[tid] =
          reinterpret_cast<const float4*>(&x[(size_t)(n0 + s) * 784])[tid];
  __syncthreads();

  if (tid < 224) {
    const int s = tid / 56, r = tid % 56, co = r / 7, oyh = r % 7;
    float wreg[25];
#pragma unroll
    for (int i = 0; i < 25; ++i) wreg[i] = wl1[co * 25 + i];
    const float bb = bl1[co];
#pragma unroll
    for (int half = 0; half < 2; ++half) {
      const int oy = oyh + half * 7;
      float acc[14];
#pragma unroll
      for (int ox = 0; ox < 14; ++ox) acc[ox] = bb;
#pragma unroll
      for (int ky = 0; ky < 5; ++ky) {
        const int y = oy * 2 - 2 + ky;
        if (y >= 0 && y < 28) {
          const float4* xp = reinterpret_cast<const float4*>(&xin[s][y * 28]);
          float xr[28];
#pragma unroll
          for (int v = 0; v < 7; ++v) {
            float4 q = xp[v];
            xr[v * 4 + 0] = q.x; xr[v * 4 + 1] = q.y;
            xr[v * 4 + 2] = q.z; xr[v * 4 + 3] = q.w;
          }
#pragma unroll
          for (int kx = 0; kx < 5; ++kx) {
            const float w = wreg[ky * 5 + kx];
#pragma unroll
            for (int ox = 0; ox < 14; ++ox) {
              const int xx = ox * 2 - 2 + kx;
              if (xx >= 0 && xx < 28) acc[ox] += w * xr[xx];
            }
          }
        }
      }
#pragma unroll
      for (int ox = 0; ox < 14; ++ox) y1p[s][co][oy][ox] = fmaxf(acc[ox], 0.f);
    }
  }
  __syncthreads();

  if (tid < 224) {
    const int s = tid / 56, r = tid % 56, cop = r / 7, oy = r % 7;
    const int co0 = cop * 2;
    float acc0[7], acc1[7];
#pragma unroll
    for (int ox = 0; ox < 7; ++ox) { acc0[ox] = bl2[co0]; acc1[ox] = bl2[co0 + 1]; }
    for (int ci = 0; ci < 8; ++ci) {
#pragma unroll
      for (int ky = 0; ky < 3; ++ky) {
        const int y = oy * 2 - 1 + ky;
        if (y >= 0 && y < 14) {
          const float4* rp = reinterpret_cast<const float4*>(&y1p[s][ci][y][0]);
          float4 q0 = rp[0], q1 = rp[1], q2 = rp[2], q3 = rp[3];
          float xr[14] = {q0.x, q0.y, q0.z, q0.w, q1.x, q1.y, q1.z, q1.w,
                          q2.x, q2.y, q2.z, q2.w, q3.x, q3.y};
          const int kb = ci * 9 + ky * 3;
          const float wa0 = wl2t[kb + 0][co0],     wa1 = wl2t[kb + 1][co0],     wa2 = wl2t[kb + 2][co0];
          const float wb0 = wl2t[kb + 0][co0 + 1], wb1 = wl2t[kb + 1][co0 + 1], wb2 = wl2t[kb + 2][co0 + 1];
#pragma unroll
          for (int ox = 0; ox < 7; ++ox) {
            if (2 * ox - 1 >= 0) { acc0[ox] += wa0 * xr[2 * ox - 1]; acc1[ox] += wb0 * xr[2 * ox - 1]; }
            acc0[ox] += wa1 * xr[2 * ox];
            acc1[ox] += wb1 * xr[2 * ox];
            if (2 * ox + 1 < 14) { acc0[ox] += wa2 * xr[2 * ox + 1]; acc1[ox] += wb2 * xr[2 * ox + 1]; }
          }
        }
      }
    }
    float* o0 = &y2p[(size_t)(n0 + s) * 896 + (co0 + 0) * 56 + oy * 8];
    float* o1 = &y2p[(size_t)(n0 + s) * 896 + (co0 + 1) * 56 + oy * 8];
#pragma unroll
    for (int ox = 0; ox < 7; ++ox) {
      o0[ox] = fmaxf(acc0[ox], 0.f);
      o1[ox] = fmaxf(acc1[ox], 0.f);
    }
  }
}

// ------------------------- conv3 + adaptive pool ---------------------------
__global__ __launch_bounds__(256) void k_conv3pool(
    const float* __restrict__ y2p,
    const float* __restrict__ w3, const float* __restrict__ b3,
    float* __restrict__ pooled) {
  __shared__ float y2s[8][16][7][8];
  __shared__ float wl3t[144][32];
  __shared__ float bl3[32];
  const int n0 = blockIdx.x * 8;
  const int tid = threadIdx.x;

  for (int i = tid; i < 4608; i += 256) {
    int k = i >> 5, co = i & 31;
    wl3t[k][co] = w3[co * 144 + k];
  }
  if (tid < 32) bl3[tid] = b3[tid];
#pragma unroll
  for (int s = 0; s < 8; ++s)
    if (tid < 224)
      reinterpret_cast<float4*>(&y2s[s][0][0][0])[tid] =
          reinterpret_cast<const float4*>(&y2p[(size_t)(n0 + s) * 896])[tid];
  __syncthreads();

  const int s = tid >> 5, co = tid & 31;
  float acc[49];
  {
    const float bb = bl3[co];
#pragma unroll
    for (int i = 0; i < 49; ++i) acc[i] = bb;
  }
  for (int ci = 0; ci < 16; ++ci) {
    float xr[7][7];
#pragma unroll
    for (int y = 0; y < 7; ++y) {
      const float4* rp = reinterpret_cast<const float4*>(&y2s[s][ci][y][0]);
      float4 qa = rp[0], qb = rp[1];
      xr[y][0] = qa.x; xr[y][1] = qa.y; xr[y][2] = qa.z; xr[y][3] = qa.w;
      xr[y][4] = qb.x; xr[y][5] = qb.y; xr[y][6] = qb.z;
    }
    float wreg[9];
#pragma unroll
    for (int k = 0; k < 9; ++k) wreg[k] = wl3t[ci * 9 + k][co];
#pragma unroll
    for (int ky = 0; ky < 3; ++ky)
#pragma unroll
      for (int kx = 0; kx < 3; ++kx) {
        const float w = wreg[ky * 3 + kx];
#pragma unroll
        for (int oy = 0; oy < 7; ++oy) {
          const int y = oy - 1 + ky;
          if (y >= 0 && y < 7) {
#pragma unroll
            for (int ox = 0; ox < 7; ++ox) {
              const int xx = ox - 1 + kx;
              if (xx >= 0 && xx < 7) acc[oy * 7 + ox] += w * xr[y][xx];
            }
          }
        }
      }
  }
#pragma unroll
  for (int i = 0; i < 49; ++i) acc[i] = fmaxf(acc[i], 0.f);
  float* out = pooled + (size_t)(n0 + s) * 288 + co * 9;
#pragma unroll
  for (int py = 0; py < 3; ++py)
#pragma unroll
    for (int px = 0; px < 3; ++px) {
      float v = 0.f;
#pragma unroll
      for (int dy = 0; dy < 3; ++dy)
#pragma unroll
        for (int dx = 0; dx < 3; ++dx) v += acc[(2 * py + dy) * 7 + (2 * px + dx)];
      out[py * 3 + px] = v * (1.f / 9.f);
    }
}

// ------------------- fp32 16-row GEMM (fc NORM, c3) ------------------------
template <int NT, int EP, bool ASYNTH>
__global__ __launch_bounds__(256) void k_rowgemm16(
    const float* __restrict__ A, const float* __restrict__ Bm,
    const float* __restrict__ bias, float* __restrict__ C,
    const float* __restrict__ sq, const float* __restrict__ sw,
    const float* __restrict__ sb, int K) {
  static_assert(NT == 128 || NT == 256, "NT");
  constexpr int NC = NT / 128;
  constexpr int NB4 = NT / 32;
  constexpr int BS = NT + 4;
  __shared__ float AT[32 * 20];
  __shared__ float BT[32 * BS];
  const int m0 = blockIdx.x * 16;
  const int tid = threadIdx.x;
  const int tr = tid >> 5, tc = tid & 31;

  float ra[2];
  float4 rb[NB4];

  auto loadAB = [&](int k0) {
#pragma unroll
    for (int e = 0; e < 2; ++e) {
      const int idx = tid + e * 256;
      const int mm = idx >> 5, kk = idx & 31;
      if (ASYNTH) ra[e] = fmaxf(sq[m0 + mm] * sw[k0 + kk] + sb[k0 + kk], 0.f);
      else ra[e] = A[(size_t)(m0 + mm) * K + k0 + kk];
    }
#pragma unroll
    for (int e = 0; e < NB4; ++e) {
      const int idx4 = tid + e * 256;
      const int nn = idx4 >> 3, kq = idx4 & 7;
      rb[e] = *reinterpret_cast<const float4*>(&Bm[(size_t)nn * K + k0 + kq * 4]);
    }
  };
  auto storeAB = [&]() {
#pragma unroll
    for (int e = 0; e < 2; ++e) {
      const int idx = tid + e * 256;
      AT[(idx & 31) * 20 + (idx >> 5)] = ra[e];
    }
#pragma unroll
    for (int e = 0; e < NB4; ++e) {
      const int idx4 = tid + e * 256;
      const int nn = idx4 >> 3, kq = idx4 & 7;
      BT[(kq * 4 + 0) * BS + nn] = rb[e].x;
      BT[(kq * 4 + 1) * BS + nn] = rb[e].y;
      BT[(kq * 4 + 2) * BS + nn] = rb[e].z;
      BT[(kq * 4 + 3) * BS + nn] = rb[e].w;
    }
  };

  float acc[2][NC][4];
#pragma unroll
  for (int i = 0; i < 2; ++i)
#pragma unroll
    for (int nc = 0; nc < NC; ++nc)
#pragma unroll
      for (int j = 0; j < 4; ++j) acc[i][nc][j] = 0.f;

  loadAB(0);
  for (int k0 = 0; k0 < K; k0 += 32) {
    __syncthreads();
    storeAB();
    __syncthreads();
    if (k0 + 32 < K) loadAB(k0 + 32);
#pragma unroll
    for (int kk = 0; kk < 32; ++kk) {
      const float2 a2 = *reinterpret_cast<const float2*>(&AT[kk * 20 + tr * 2]);
#pragma unroll
      for (int nc = 0; nc < NC; ++nc) {
        const float4 b4 = *reinterpret_cast<const float4*>(
            &BT[kk * BS + nc * 128 + tc * 4]);
        acc[0][nc][0] += a2.x * b4.x; acc[0][nc][1] += a2.x * b4.y;
        acc[0][nc][2] += a2.x * b4.z; acc[0][nc][3] += a2.x * b4.w;
        acc[1][nc][0] += a2.y * b4.x; acc[1][nc][1] += a2.y * b4.y;
        acc[1][nc][2] += a2.y * b4.z; acc[1][nc][3] += a2.y * b4.w;
      }
    }
  }

  if (EP == 2) {
    float qp[2] = {0.f, 0.f};
#pragma unroll
    for (int i = 0; i < 2; ++i)
#pragma unroll
      for (int nc = 0; nc < NC; ++nc)
#pragma unroll
        for (int j = 0; j < 4; ++j) {
          const float v = acc[i][nc][j];
          qp[i] += (nc == 0) ? v * v : -v * v;
        }
#pragma unroll
    for (int i = 0; i < 2; ++i)
#pragma unroll
      for (int d = 1; d < 32; d <<= 1) qp[i] += __shfl_xor(qp[i], d, 64);
    if (tc == 0) {
#pragma unroll
      for (int i = 0; i < 2; ++i) C[m0 + tr * 2 + i] = qp[i];
    }
  } else if (EP == 1) {
    float t[2][NC][4];
    float ss[2] = {0.f, 0.f};
#pragma unroll
    for (int i = 0; i < 2; ++i)
#pragma unroll
      for (int nc = 0; nc < NC; ++nc)
#pragma unroll
        for (int j = 0; j < 4; ++j) {
          const float v = fmaxf(acc[i][nc][j] + bias[nc * 128 + tc * 4 + j], 0.f);
          t[i][nc][j] = v;
          ss[i] += v * v;
        }
#pragma unroll
    for (int i = 0; i < 2; ++i)
#pragma unroll
      for (int d = 1; d < 32; d <<= 1) ss[i] += __shfl_xor(ss[i], d, 64);
#pragma unroll
    for (int i = 0; i < 2; ++i) {
      const float sc = 1.f / fmaxf(sqrtf(ss[i]), 1e-12f);
#pragma unroll
      for (int nc = 0; nc < NC; ++nc) {
        float4 v;
        v.x = t[i][nc][0] * sc; v.y = t[i][nc][1] * sc;
        v.z = t[i][nc][2] * sc; v.w = t[i][nc][3] * sc;
        *reinterpret_cast<float4*>(&C[(size_t)(m0 + tr * 2 + i) * NT + nc * 128 + tc * 4]) = v;
      }
    }
  } else {
#pragma unroll
    for (int i = 0; i < 2; ++i)
#pragma unroll
      for (int nc = 0; nc < NC; ++nc) {
        float4 v;
        v.x = fmaxf(acc[i][nc][0] + bias[nc * 128 + tc * 4 + 0], 0.f);
        v.y = fmaxf(acc[i][nc][1] + bias[nc * 128 + tc * 4 + 1], 0.f);
        v.z = fmaxf(acc[i][nc][2] + bias[nc * 128 + tc * 4 + 2], 0.f);
        v.w = fmaxf(acc[i][nc][3] + bias[nc * 128 + tc * 4 + 3], 0.f);
        *reinterpret_cast<float4*>(&C[(size_t)(m0 + tr * 2 + i) * NT + nc * 128 + tc * 4]) = v;
      }
  }
}

// ------------------- fp32 64-row GEMM (tiny c4 layer) ----------------------
template <int NT>
__global__ __launch_bounds__(256) void k_rowgemm64(
    const float* __restrict__ A, const float* __restrict__ Bm,
    const float* __restrict__ bias, float* __restrict__ C, int K) {
  constexpr int NB = NT / 64;
  __shared__ float AT[32 * 68];
  __shared__ float BT[32 * (NT + 4)];
  constexpr int BS = NT + 4;
  const int m0 = blockIdx.x * 64;
  const int tid = threadIdx.x;
  const int tr = tid >> 4, tc = tid & 15;
  float acc[4][NB][4];
#pragma unroll
  for (int i = 0; i < 4; ++i)
#pragma unroll
    for (int nb = 0; nb < NB; ++nb)
#pragma unroll
      for (int j = 0; j < 4; ++j) acc[i][nb][j] = 0.f;

  for (int k0 = 0; k0 < K; k0 += 32) {
#pragma unroll
    for (int e = 0; e < 8; ++e) {
      int idx = tid + e * 256;
      int mm = idx >> 5, kk = idx & 31;
      AT[kk * 68 + mm] = A[(size_t)(m0 + mm) * K + k0 + kk];
    }
#pragma unroll
    for (int e = 0; e < NB * 8; ++e) {
      int idx = tid + e * 256;
      int nn = idx >> 5, kk = idx & 31;
      BT[kk * BS + nn] = Bm[(size_t)nn * K + k0 + kk];
    }
    __syncthreads();
#pragma unroll
    for (int kk = 0; kk < 32; ++kk) {
      const float4 a4 = *reinterpret_cast<const float4*>(&AT[kk * 68 + tr * 4]);
      const float a[4] = {a4.x, a4.y, a4.z, a4.w};
#pragma unroll
      for (int nb = 0; nb < NB; ++nb) {
        const float4 b4 = *reinterpret_cast<const float4*>(&BT[kk * BS + nb * 64 + tc * 4]);
        const float b[4] = {b4.x, b4.y, b4.z, b4.w};
#pragma unroll
        for (int i = 0; i < 4; ++i)
#pragma unroll
          for (int j = 0; j < 4; ++j) acc[i][nb][j] += a[i] * b[j];
      }
    }
    __syncthreads();
  }
#pragma unroll
  for (int i = 0; i < 4; ++i)
#pragma unroll
    for (int nb = 0; nb < NB; ++nb) {
      float4 v;
      v.x = fmaxf(acc[i][nb][0] + bias[nb * 64 + tc * 4 + 0], 0.f);
      v.y = fmaxf(acc[i][nb][1] + bias[nb * 64 + tc * 4 + 1], 0.f);
      v.z = fmaxf(acc[i][nb][2] + bias[nb * 64 + tc * 4 + 2], 0.f);
      v.w = fmaxf(acc[i][nb][3] + bias[nb * 64 + tc * 4 + 3], 0.f);
      *reinterpret_cast<float4*>(&C[(size_t)(m0 + tr * 4 + i) * NT + nb * 64 + tc * 4]) = v;
    }
}

// ---------------- weight split: fp32 -> bf16 hi/lo -------------------------
__global__ __launch_bounds__(256) void k_splitW(const float* __restrict__ W,
                                                short* __restrict__ Wh,
                                                short* __restrict__ Wl, int n) {
  const int i = blockIdx.x * 256 + threadIdx.x;
  if (i < n) {
    const float x = W[i];
    const unsigned hb = rne_bf16(x);
    const float lo = x - __uint_as_float(hb);
    Wh[i] = (short)(hb >> 16);
    Wl[i] = (short)(rne_bf16(lo) >> 16);
  }
}

// ------------------------- quantum circuit -> U (bf16 splits) --------------
__global__ __launch_bounds__(64) void k_buildU(const float* __restrict__ qw,
                                               short* __restrict__ Uh,
                                               short* __restrict__ Ul) {
  const int j = blockIdx.x;
  const int t = threadIdx.x;
  float a0 = (t == j) ? 1.f : 0.f;
  float a1 = (64 + t == j) ? 1.f : 0.f;
  float a2 = (128 + t == j) ? 1.f : 0.f;
  float a3 = (192 + t == j) ? 1.f : 0.f;
  for (int l = 0; l < 7; ++l) {
#pragma unroll
    for (int q = 0; q < 8; ++q) {
      const float th = 0.5f * qw[l * 8 + q];
      const float c = cosf(th), s = sinf(th);
      const int m = 7 - q;
      if (m == 7) {
        const float n0 = c * a0 - s * a2, n2 = s * a0 + c * a2;
        const float n1 = c * a1 - s * a3, n3 = s * a1 + c * a3;
        a0 = n0; a2 = n2; a1 = n1; a3 = n3;
      } else if (m == 6) {
        const float n0 = c * a0 - s * a1, n1 = s * a0 + c * a1;
        const float n2 = c * a2 - s * a3, n3 = s * a2 + c * a3;
        a0 = n0; a1 = n1; a2 = n2; a3 = n3;
      } else {
        const float p0 = __shfl_xor(a0, 1 << m, 64);
        const float p1 = __shfl_xor(a1, 1 << m, 64);
        const float p2 = __shfl_xor(a2, 1 << m, 64);
        const float p3 = __shfl_xor(a3, 1 << m, 64);
        const float sgn = ((t >> m) & 1) ? s : -s;
        a0 = c * a0 + sgn * p0; a1 = c * a1 + sgn * p1;
        a2 = c * a2 + sgn * p2; a3 = c * a3 + sgn * p3;
      }
    }
#pragma unroll
    for (int q = 0; q < 7; ++q) {
      const int mc = 7 - q, mt = mc - 1;
      if (mc == 7) {
        const float tmp = a2; a2 = a3; a3 = tmp;
      } else if (mc == 6) {
        a1 = __shfl_xor(a1, 32, 64);
        a3 = __shfl_xor(a3, 32, 64);
      } else {
        const float p0 = __shfl_xor(a0, 1 << mt, 64);
        const float p1 = __shfl_xor(a1, 1 << mt, 64);
        const float p2 = __shfl_xor(a2, 1 << mt, 64);
        const float p3 = __shfl_xor(a3, 1 << mt, 64);
        if ((t >> mc) & 1) { a0 = p0; a1 = p1; a2 = p2; a3 = p3; }
      }
    }
  }
  const float av[4] = {a0, a1, a2, a3};
#pragma unroll
  for (int r = 0; r < 4; ++r) {
    const float x = av[r];
    const unsigned hb = rne_bf16(x);
    const float lo = x - __uint_as_float(hb);
    Uh[(r * 64 + t) * 256 + j] = (short)(hb >> 16);
    Ul[(r * 64 + t) * 256 + j] = (short)(rne_bf16(lo) >> 16);
  }
}

// ---------------- split-bf16 MFMA GEMM, LDS-free ---------------------------
// C[16 x 256] per block (grid M/16=512); 4 waves x 4 n-tiles of 16x16x32 MFMA.
// A fragment: lane holds A[m0 + (lane&15)][kb + i], kb = k0 + (lane>>4)*8.
// B fragment: lane holds B[k][n0+nt*16+(lane&15)] = W[n][k] contiguous in k.
// D fragment: row = m0 + (lane>>4)*4 + j, col = n0 + nt*16 + (lane&15).
// MODE 0: A synthesized = relu(sq[m]*sw[k]+sb[k]); out = relu(D + bias).
// MODE 1: A = Afp (global); out = qv[m] = sum_{n<128} D^2 - sum_{n>=128} D^2.
template <int MODE>
__global__ __launch_bounds__(256) void k_mfma16(
    const float* __restrict__ Afp, const short* __restrict__ Bh,
    const short* __restrict__ Bl, const float* __restrict__ bias,
    float* __restrict__ Cout, const float* __restrict__ sq,
    const float* __restrict__ sw, const float* __restrict__ sb, int K) {
  __shared__ float red[4][16];
  const int m0 = blockIdx.x * 16;
  const int tid = threadIdx.x;
  const int wave = tid >> 6, lane = tid & 63;
  const int lrow = lane & 15, lgrp = lane >> 4;
  const int n0 = wave * 64;

  f32x4 acc[4];
#pragma unroll
  for (int nt = 0; nt < 4; ++nt) acc[nt] = (f32x4){0.f, 0.f, 0.f, 0.f};

  float qm = 0.f;
  if (MODE == 0) qm = sq[m0 + lrow];
  const float* arow = (MODE == 1) ? (Afp + (size_t)(m0 + lrow) * K) : Afp;

  for (int k0 = 0; k0 < K; k0 += 32) {
    const int kb = k0 + lgrp * 8;
    float a[8];
    if (MODE == 0) {
      const float4 w0 = *reinterpret_cast<const float4*>(&sw[kb]);
      const float4 w1 = *reinterpret_cast<const float4*>(&sw[kb + 4]);
      const float4 b0 = *reinterpret_cast<const float4*>(&sb[kb]);
      const float4 b1 = *reinterpret_cast<const float4*>(&sb[kb + 4]);
      a[0] = fmaxf(qm * w0.x + b0.x, 0.f); a[1] = fmaxf(qm * w0.y + b0.y, 0.f);
      a[2] = fmaxf(qm * w0.z + b0.z, 0.f); a[3] = fmaxf(qm * w0.w + b0.w, 0.f);
      a[4] = fmaxf(qm * w1.x + b1.x, 0.f); a[5] = fmaxf(qm * w1.y + b1.y, 0.f);
      a[6] = fmaxf(qm * w1.z + b1.z, 0.f); a[7] = fmaxf(qm * w1.w + b1.w, 0.f);
    } else {
      const float4 a0v = *reinterpret_cast<const float4*>(&arow[kb]);
      const float4 a1v = *reinterpret_cast<const float4*>(&arow[kb + 4]);
      a[0] = a0v.x; a[1] = a0v.y; a[2] = a0v.z; a[3] = a0v.w;
      a[4] = a1v.x; a[5] = a1v.y; a[6] = a1v.z; a[7] = a1v.w;
    }
    bf16x8 ah, al;
#pragma unroll
    for (int i = 0; i < 8; ++i) {
      const unsigned hb = rne_bf16(a[i]);
      const float lo = a[i] - __uint_as_float(hb);
      ah[i] = (short)(hb >> 16);
      al[i] = (short)(rne_bf16(lo) >> 16);
    }
#pragma unroll
    for (int nt = 0; nt < 4; ++nt) {
      const size_t boff = (size_t)(n0 + nt * 16 + lrow) * K + kb;
      const bf16x8 bh = *reinterpret_cast<const bf16x8*>(&Bh[boff]);
      const bf16x8 bl = *reinterpret_cast<const bf16x8*>(&Bl[boff]);
      acc[nt] = __builtin_amdgcn_mfma_f32_16x16x32_bf16(ah, bh, acc[nt], 0, 0, 0);
      acc[nt] = __builtin_amdgcn_mfma_f32_16x16x32_bf16(ah, bl, acc[nt], 0, 0, 0);
      acc[nt] = __builtin_amdgcn_mfma_f32_16x16x32_bf16(al, bh, acc[nt], 0, 0, 0);
    }
  }

  if (MODE == 0) {
#pragma unroll
    for (int nt = 0; nt < 4; ++nt) {
      const int col = n0 + nt * 16 + lrow;
      const float bb = bias[col];
#pragma unroll
      for (int j = 0; j < 4; ++j) {
        const int row = m0 + lgrp * 4 + j;
        Cout[(size_t)row * 256 + col] = fmaxf(acc[nt][j] + bb, 0.f);
      }
    }
  } else {
    float p[4] = {0.f, 0.f, 0.f, 0.f};
#pragma unroll
    for (int nt = 0; nt < 4; ++nt)
#pragma unroll
      for (int j = 0; j < 4; ++j) { const float v = acc[nt][j]; p[j] += v * v; }
    if (wave >= 2) {
#pragma unroll
      for (int j = 0; j < 4; ++j) p[j] = -p[j];
    }
#pragma unroll
    for (int d = 1; d < 16; d <<= 1)
#pragma unroll
      for (int j = 0; j < 4; ++j) p[j] += __shfl_xor(p[j], d, 64);
    if (lrow == 0) {
#pragma unroll
      for (int j = 0; j < 4; ++j) red[wave][lgrp * 4 + j] = p[j];
    }
    __syncthreads();
    if (tid < 16)
      Cout[m0 + tid] = red[0][tid] + red[1][tid] + red[2][tid] + red[3][tid];
  }
}

// ------------------------- final layer -------------------------------------
__global__ __launch_bounds__(256) void k_head5(const float* __restrict__ h4,
                                               const float* __restrict__ w,
                                               const float* __restrict__ b,
                                               float* __restrict__ out) {
  const int row = blockIdx.x * 4 + (threadIdx.x >> 6);
  const int lane = threadIdx.x & 63;
  float s = h4[(size_t)row * 64 + lane] * w[lane];
#pragma unroll
  for (int d = 32; d > 0; d >>= 1) s += __shfl_xor(s, d, 64);
  if (lane == 0) out[row] = 1.f / (1.f + expf(-(s + b[0])));
}

// ---------------------------------------------------------------------------
extern "C" void kernel_launch(void* const* d_in, const int* in_sizes, int n_in,
                              void* d_out, int out_size, void* d_ws, size_t ws_size,
                              hipStream_t stream) {
  const float* x       = (const float*)d_in[0];
  const float* conv1_w = (const float*)d_in[1];
  const float* conv1_b = (const float*)d_in[2];
  const float* conv2_w = (const float*)d_in[3];
  const float* conv2_b = (const float*)d_in[4];
  const float* conv3_w = (const float*)d_in[5];
  const float* conv3_b = (const float*)d_in[6];
  const float* fc_w    = (const float*)d_in[7];
  const float* fc_b    = (const float*)d_in[8];
  const float* q_w     = (const float*)d_in[9];
  const float* c1_w    = (const float*)d_in[10];
  const float* c1_b    = (const float*)d_in[11];
  const float* c2_w    = (const float*)d_in[12];
  const float* c2_b    = (const float*)d_in[13];
  const float* c3_w    = (const float*)d_in[14];
  const float* c3_b    = (const float*)d_in[15];
  const float* c4_w    = (const float*)d_in[16];
  const float* c4_b    = (const float*)d_in[17];
  const float* c5_w    = (const float*)d_in[18];
  const float* c5_b    = (const float*)d_in[19];
  float* out = (float*)d_out;
  char* ws = (char*)d_ws;

  // workspace layout (peak ~39.3 MB)
  float* y2p    = (float*)(ws + 0);          // 29,360,128
  float* pooled = (float*)(ws + 29360128);   //  9,437,184 (ends 38,797,312)
  short* c2h    = (short*)(ws + 38797312);   //    262,144
  short* c2l    = (short*)(ws + 39059456);   //    262,144 (ends 39,321,600)
  float* feat   = (float*)(ws + 0);          //  8,388,608 (y2p dead)
  short* Uh     = (short*)(ws + 8388608);    //    131,072
  short* Ul     = (short*)(ws + 8519680);    //    131,072
  float* qv     = (float*)(ws + 8650752);    //     32,768
  float* h2     = (float*)(ws + 8683520);    //  8,388,608
  float* h3     = (float*)(ws + 17072128);   //  4,194,304
  float* h4     = (float*)(ws + 21266432);   //  2,097,152
  (void)in_sizes; (void)n_in; (void)out_size; (void)ws_size;

  // c2_w split (independent of activations)
  k_splitW<<<512, 256, 0, stream>>>(c2_w, c2h, c2l, 256 * 512);

  k_conv12<<<2048, 256, 0, stream>>>(x, conv1_w, conv1_b, conv2_w, conv2_b, y2p);
  k_conv3pool<<<1024, 256, 0, stream>>>(y2p, conv3_w, conv3_b, pooled);
  // fc (K=288) + relu + L2-normalize rows -> feat  [fp32]
  k_rowgemm16<256, 1, false><<<512, 256, 0, stream>>>(pooled, fc_w, fc_b, feat,
                                                      nullptr, nullptr, nullptr, 288);
  k_buildU<<<256, 64, 0, stream>>>(q_w, Uh, Ul);
  // qv = signed square-sum of (feat @ U^T)   [MFMA split-bf16]
  k_mfma16<1><<<512, 256, 0, stream>>>(feat, Uh, Ul, nullptr, qv,
                                       nullptr, nullptr, nullptr, 256);
  // h2 = relu(relu(q*c1w+c1b) @ c2^T + c2b)  [MFMA split-bf16, A synthesized]
  k_mfma16<0><<<512, 256, 0, stream>>>(nullptr, c2h, c2l, c2_b, h2,
                                       qv, c1_w, c1_b, 512);
  // h3 = relu(h2 @ c3^T + c3b)  [fp32]
  k_rowgemm16<128, 0, false><<<512, 256, 0, stream>>>(h2, c3_w, c3_b, h3,
                                                      nullptr, nullptr, nullptr, 256);
  // h4 = relu(h3 @ c4^T + c4b)  [fp32]
  k_rowgemm64<64><<<128, 256, 0, stream>>>(h3, c4_w, c4_b, h4, 128);
  k_head5<<<2048, 256, 0, stream>>>(h4, c5_w, c5_b, out);
}

// Round 10
// 324.519 us; speedup vs baseline: 2.0409x; 1.0124x over previous
//
#include <hip/hip_runtime.h>
#include <math.h>

// ---------------------------------------------------------------------------
// Precise45K CNN+QNN forward.
//  k_conv12    : conv1+conv2 fused in LDS                   [fp32, validated]
//  k_conv3pool : conv3 + adaptive pool                      [fp32, validated]
//  k_mfma2     : split-bf16 MFMA GEMM, LDS-free, N-split grid (512,2),
//                4 waves/SIMD. MODE 0=FC (out feat + rs partials),
//                1=QSUM (out qp partials, ny=1 negated), 2=C2 (A synthesized
//                from qp/rs/c1w/c1b; out h2). D=Ah*Bh+Ah*Bl+Al*Bh.
//                Normalization is DEFERRED: q = (qp0+qp1)/max(rs0+rs1,eps).
//  k_rowgemm16 : fp32 GEMM for c3                           [validated]
//  k_rowgemm64 : fp32 GEMM for tiny c4                      [validated]
//  k_buildU    : quantum circuit -> U bf16 hi/lo            [validated]
//  k_splitW    : fp32 weights -> bf16 hi/lo                 [validated]
//  k_head5     : final dot(64) + sigmoid                    [validated]
// ---------------------------------------------------------------------------

typedef __attribute__((ext_vector_type(8))) short bf16x8;
typedef __attribute__((ext_vector_type(4))) float f32x4;

__device__ __forceinline__ unsigned rne_bf16(float x) {
  unsigned u = __float_as_uint(x);
  return (u + 0x7FFFu + ((u >> 16) & 1u)) & 0xFFFF0000u;
}

// ------------------------- conv1 + conv2 -----------------------------------
__global__ __launch_bounds__(256) void k_conv12(
    const float* __restrict__ x,
    const float* __restrict__ w1, const float* __restrict__ b1,
    const float* __restrict__ w2, const float* __restrict__ b2,
    float* __restrict__ y2p) {
  __shared__ float xin[4][784];
  __shared__ float y1p[4][8][14][20];
  __shared__ float wl1[200], bl1[8];
  __shared__ float wl2t[72][16], bl2[16];
  const int n0 = blockIdx.x * 4;
  const int tid = threadIdx.x;

  for (int i = tid; i < 200; i += 256) wl1[i] = w1[i];
  if (tid < 8) bl1[tid] = b1[tid];
  for (int i = tid; i < 1152; i += 256) {
    int k = i >> 4, co = i & 15;
    wl2t[k][co] = w2[co * 72 + k];
  }
  if (tid < 16) bl2[tid] = b2[tid];
#pragma unroll
  for (int s = 0; s < 4; ++s)
    if (tid < 196)
      reinterpret_cast<float4*>(&xin[s][0])[tid] =
          reinterpret_cast<const float4*>(&x[(size_t)(n0 + s) * 784])[tid];
  __syncthreads();

  if (tid < 224) {
    const int s = tid / 56, r = tid % 56, co = r / 7, oyh = r % 7;
    float wreg[25];
#pragma unroll
    for (int i = 0; i < 25; ++i) wreg[i] = wl1[co * 25 + i];
    const float bb = bl1[co];
#pragma unroll
    for (int half = 0; half < 2; ++half) {
      const int oy = oyh + half * 7;
      float acc[14];
#pragma unroll
      for (int ox = 0; ox < 14; ++ox) acc[ox] = bb;
#pragma unroll
      for (int ky = 0; ky < 5; ++ky) {
        const int y = oy * 2 - 2 + ky;
        if (y >= 0 && y < 28) {
          const float4* xp = reinterpret_cast<const float4*>(&xin[s][y * 28]);
          float xr[28];
#pragma unroll
          for (int v = 0; v < 7; ++v) {
            float4 q = xp[v];
            xr[v * 4 + 0] = q.x; xr[v * 4 + 1] = q.y;
            xr[v * 4 + 2] = q.z; xr[v * 4 + 3] = q.w;
          }
#pragma unroll
          for (int kx = 0; kx < 5; ++kx) {
            const float w = wreg[ky * 5 + kx];
#pragma unroll
            for (int ox = 0; ox < 14; ++ox) {
              const int xx = ox * 2 - 2 + kx;
              if (xx >= 0 && xx < 28) acc[ox] += w * xr[xx];
            }
          }
        }
      }
#pragma unroll
      for (int ox = 0; ox < 14; ++ox) y1p[s][co][oy][ox] = fmaxf(acc[ox], 0.f);
    }
  }
  __syncthreads();

  if (tid < 224) {
    const int s = tid / 56, r = tid % 56, cop = r / 7, oy = r % 7;
    const int co0 = cop * 2;
    float acc0[7], acc1[7];
#pragma unroll
    for (int ox = 0; ox < 7; ++ox) { acc0[ox] = bl2[co0]; acc1[ox] = bl2[co0 + 1]; }
    for (int ci = 0; ci < 8; ++ci) {
#pragma unroll
      for (int ky = 0; ky < 3; ++ky) {
        const int y = oy * 2 - 1 + ky;
        if (y >= 0 && y < 14) {
          const float4* rp = reinterpret_cast<const float4*>(&y1p[s][ci][y][0]);
          float4 q0 = rp[0], q1 = rp[1], q2 = rp[2], q3 = rp[3];
          float xr[14] = {q0.x, q0.y, q0.z, q0.w, q1.x, q1.y, q1.z, q1.w,
                          q2.x, q2.y, q2.z, q2.w, q3.x, q3.y};
          const int kb = ci * 9 + ky * 3;
          const float wa0 = wl2t[kb + 0][co0],     wa1 = wl2t[kb + 1][co0],     wa2 = wl2t[kb + 2][co0];
          const float wb0 = wl2t[kb + 0][co0 + 1], wb1 = wl2t[kb + 1][co0 + 1], wb2 = wl2t[kb + 2][co0 + 1];
#pragma unroll
          for (int ox = 0; ox < 7; ++ox) {
            if (2 * ox - 1 >= 0) { acc0[ox] += wa0 * xr[2 * ox - 1]; acc1[ox] += wb0 * xr[2 * ox - 1]; }
            acc0[ox] += wa1 * xr[2 * ox];
            acc1[ox] += wb1 * xr[2 * ox];
            if (2 * ox + 1 < 14) { acc0[ox] += wa2 * xr[2 * ox + 1]; acc1[ox] += wb2 * xr[2 * ox + 1]; }
          }
        }
      }
    }
    float* o0 = &y2p[(size_t)(n0 + s) * 896 + (co0 + 0) * 56 + oy * 8];
    float* o1 = &y2p[(size_t)(n0 + s) * 896 + (co0 + 1) * 56 + oy * 8];
#pragma unroll
    for (int ox = 0; ox < 7; ++ox) {
      o0[ox] = fmaxf(acc0[ox], 0.f);
      o1[ox] = fmaxf(acc1[ox], 0.f);
    }
  }
}

// ------------------------- conv3 + adaptive pool ---------------------------
__global__ __launch_bounds__(256) void k_conv3pool(
    const float* __restrict__ y2p,
    const float* __restrict__ w3, const float* __restrict__ b3,
    float* __restrict__ pooled) {
  __shared__ float y2s[8][16][7][8];
  __shared__ float wl3t[144][32];
  __shared__ float bl3[32];
  const int n0 = blockIdx.x * 8;
  const int tid = threadIdx.x;

  for (int i = tid; i < 4608; i += 256) {
    int k = i >> 5, co = i & 31;
    wl3t[k][co] = w3[co * 144 + k];
  }
  if (tid < 32) bl3[tid] = b3[tid];
#pragma unroll
  for (int s = 0; s < 8; ++s)
    if (tid < 224)
      reinterpret_cast<float4*>(&y2s[s][0][0][0])[tid] =
          reinterpret_cast<const float4*>(&y2p[(size_t)(n0 + s) * 896])[tid];
  __syncthreads();

  const int s = tid >> 5, co = tid & 31;
  float acc[49];
  {
    const float bb = bl3[co];
#pragma unroll
    for (int i = 0; i < 49; ++i) acc[i] = bb;
  }
  for (int ci = 0; ci < 16; ++ci) {
    float xr[7][7];
#pragma unroll
    for (int y = 0; y < 7; ++y) {
      const float4* rp = reinterpret_cast<const float4*>(&y2s[s][ci][y][0]);
      float4 qa = rp[0], qb = rp[1];
      xr[y][0] = qa.x; xr[y][1] = qa.y; xr[y][2] = qa.z; xr[y][3] = qa.w;
      xr[y][4] = qb.x; xr[y][5] = qb.y; xr[y][6] = qb.z;
    }
    float wreg[9];
#pragma unroll
    for (int k = 0; k < 9; ++k) wreg[k] = wl3t[ci * 9 + k][co];
#pragma unroll
    for (int ky = 0; ky < 3; ++ky)
#pragma unroll
      for (int kx = 0; kx < 3; ++kx) {
        const float w = wreg[ky * 3 + kx];
#pragma unroll
        for (int oy = 0; oy < 7; ++oy) {
          const int y = oy - 1 + ky;
          if (y >= 0 && y < 7) {
#pragma unroll
            for (int ox = 0; ox < 7; ++ox) {
              const int xx = ox - 1 + kx;
              if (xx >= 0 && xx < 7) acc[oy * 7 + ox] += w * xr[y][xx];
            }
          }
        }
      }
  }
#pragma unroll
  for (int i = 0; i < 49; ++i) acc[i] = fmaxf(acc[i], 0.f);
  float* out = pooled + (size_t)(n0 + s) * 288 + co * 9;
#pragma unroll
  for (int py = 0; py < 3; ++py)
#pragma unroll
    for (int px = 0; px < 3; ++px) {
      float v = 0.f;
#pragma unroll
      for (int dy = 0; dy < 3; ++dy)
#pragma unroll
        for (int dx = 0; dx < 3; ++dx) v += acc[(2 * py + dy) * 7 + (2 * px + dx)];
      out[py * 3 + px] = v * (1.f / 9.f);
    }
}

// ---------------- split-bf16 MFMA GEMM, LDS-free, N-split ------------------
// grid (M/16, 2); 256 thr = 4 waves; wave covers 32 cols (2 16x16 n-tiles).
// Global col = ny*128 + wave*32 + nt*16 + (lane&15). K compile-time.
// MODE 0 (FC):   A=Afp rows (K=288); out: Cout=feat(relu(D+bias)) and
//                aux: rs[ny*8192+m] = partial row sum of squares.
// MODE 1 (QSUM): A=Afp rows (K=256); out: Cout=qp[ny*8192+m] = partial
//                sum of squares, NEGATED for ny=1.
// MODE 2 (C2):   A synthesized: qm=(qp0+qp1)/max(rs0+rs1,1e-24);
//                a[k]=relu(qm*sw[k]+sb[k]); out: Cout=relu(D+bias).
template <int MODE, int K>
__global__ __launch_bounds__(256, 4) void k_mfma2(
    const float* __restrict__ Afp, const short* __restrict__ Bh,
    const short* __restrict__ Bl, const float* __restrict__ bias,
    float* __restrict__ Cout, float* __restrict__ aux,
    const float* __restrict__ qp, const float* __restrict__ rs,
    const float* __restrict__ sw, const float* __restrict__ sb) {
  __shared__ float red[4][16];
  const int m0 = blockIdx.x * 16;
  const int ny = blockIdx.y;
  const int tid = threadIdx.x;
  const int wave = tid >> 6, lane = tid & 63;
  const int lrow = lane & 15, lgrp = lane >> 4;
  const int colg = ny * 128 + wave * 32;

  f32x4 acc[2];
  acc[0] = (f32x4){0.f, 0.f, 0.f, 0.f};
  acc[1] = (f32x4){0.f, 0.f, 0.f, 0.f};

  float qm = 0.f;
  if (MODE == 2) {
    const int m = m0 + lrow;
    const float num = qp[m] + qp[8192 + m];
    const float den = fmaxf(rs[m] + rs[8192 + m], 1e-24f);
    qm = num / den;
  }
  const float* arow = (MODE == 2) ? nullptr : (Afp + (size_t)(m0 + lrow) * K);

#pragma unroll 4
  for (int k0 = 0; k0 < K; k0 += 32) {
    const int kb = k0 + lgrp * 8;
    float a[8];
    if (MODE == 2) {
      const float4 w0 = *reinterpret_cast<const float4*>(&sw[kb]);
      const float4 w1 = *reinterpret_cast<const float4*>(&sw[kb + 4]);
      const float4 b0 = *reinterpret_cast<const float4*>(&sb[kb]);
      const float4 b1 = *reinterpret_cast<const float4*>(&sb[kb + 4]);
      a[0] = fmaxf(qm * w0.x + b0.x, 0.f); a[1] = fmaxf(qm * w0.y + b0.y, 0.f);
      a[2] = fmaxf(qm * w0.z + b0.z, 0.f); a[3] = fmaxf(qm * w0.w + b0.w, 0.f);
      a[4] = fmaxf(qm * w1.x + b1.x, 0.f); a[5] = fmaxf(qm * w1.y + b1.y, 0.f);
      a[6] = fmaxf(qm * w1.z + b1.z, 0.f); a[7] = fmaxf(qm * w1.w + b1.w, 0.f);
    } else {
      const float4 a0v = *reinterpret_cast<const float4*>(&arow[kb]);
      const float4 a1v = *reinterpret_cast<const float4*>(&arow[kb + 4]);
      a[0] = a0v.x; a[1] = a0v.y; a[2] = a0v.z; a[3] = a0v.w;
      a[4] = a1v.x; a[5] = a1v.y; a[6] = a1v.z; a[7] = a1v.w;
    }
    bf16x8 ah, al;
#pragma unroll
    for (int i = 0; i < 8; ++i) {
      const unsigned hb = rne_bf16(a[i]);
      const float lo = a[i] - __uint_as_float(hb);
      ah[i] = (short)(hb >> 16);
      al[i] = (short)(rne_bf16(lo) >> 16);
    }
#pragma unroll
    for (int nt = 0; nt < 2; ++nt) {
      const size_t boff = (size_t)(colg + nt * 16 + lrow) * K + kb;
      const bf16x8 bh = *reinterpret_cast<const bf16x8*>(&Bh[boff]);
      const bf16x8 bl = *reinterpret_cast<const bf16x8*>(&Bl[boff]);
      acc[nt] = __builtin_amdgcn_mfma_f32_16x16x32_bf16(ah, bh, acc[nt], 0, 0, 0);
      acc[nt] = __builtin_amdgcn_mfma_f32_16x16x32_bf16(ah, bl, acc[nt], 0, 0, 0);
      acc[nt] = __builtin_amdgcn_mfma_f32_16x16x32_bf16(al, bh, acc[nt], 0, 0, 0);
    }
  }

  if (MODE == 1) {
    float p[4] = {0.f, 0.f, 0.f, 0.f};
#pragma unroll
    for (int nt = 0; nt < 2; ++nt)
#pragma unroll
      for (int j = 0; j < 4; ++j) { const float v = acc[nt][j]; p[j] += v * v; }
#pragma unroll
    for (int d = 1; d < 16; d <<= 1)
#pragma unroll
      for (int j = 0; j < 4; ++j) p[j] += __shfl_xor(p[j], d, 64);
    if (lrow == 0) {
#pragma unroll
      for (int j = 0; j < 4; ++j) red[wave][lgrp * 4 + j] = p[j];
    }
    __syncthreads();
    if (tid < 16) {
      const float v = red[0][tid] + red[1][tid] + red[2][tid] + red[3][tid];
      Cout[ny * 8192 + m0 + tid] = ny ? -v : v;
    }
  } else {
    float p[4] = {0.f, 0.f, 0.f, 0.f};
#pragma unroll
    for (int nt = 0; nt < 2; ++nt) {
      const int col = colg + nt * 16 + lrow;
      const float bb = bias[col];
#pragma unroll
      for (int j = 0; j < 4; ++j) {
        const int row = m0 + lgrp * 4 + j;
        const float v = fmaxf(acc[nt][j] + bb, 0.f);
        Cout[(size_t)row * 256 + col] = v;
        if (MODE == 0) p[j] += v * v;
      }
    }
    if (MODE == 0) {
#pragma unroll
      for (int d = 1; d < 16; d <<= 1)
#pragma unroll
        for (int j = 0; j < 4; ++j) p[j] += __shfl_xor(p[j], d, 64);
      if (lrow == 0) {
#pragma unroll
        for (int j = 0; j < 4; ++j) red[wave][lgrp * 4 + j] = p[j];
      }
      __syncthreads();
      if (tid < 16)
        aux[ny * 8192 + m0 + tid] =
            red[0][tid] + red[1][tid] + red[2][tid] + red[3][tid];
    }
  }
}

// ------------------- fp32 16-row GEMM (c3) ---------------------------------
template <int NT, int EP, bool ASYNTH>
__global__ __launch_bounds__(256) void k_rowgemm16(
    const float* __restrict__ A, const float* __restrict__ Bm,
    const float* __restrict__ bias, float* __restrict__ C,
    const float* __restrict__ sq, const float* __restrict__ sw,
    const float* __restrict__ sb, int K) {
  static_assert(NT == 128 || NT == 256, "NT");
  constexpr int NC = NT / 128;
  constexpr int NB4 = NT / 32;
  constexpr int BS = NT + 4;
  __shared__ float AT[32 * 20];
  __shared__ float BT[32 * BS];
  const int m0 = blockIdx.x * 16;
  const int tid = threadIdx.x;
  const int tr = tid >> 5, tc = tid & 31;

  float ra[2];
  float4 rb[NB4];

  auto loadAB = [&](int k0) {
#pragma unroll
    for (int e = 0; e < 2; ++e) {
      const int idx = tid + e * 256;
      const int mm = idx >> 5, kk = idx & 31;
      if (ASYNTH) ra[e] = fmaxf(sq[m0 + mm] * sw[k0 + kk] + sb[k0 + kk], 0.f);
      else ra[e] = A[(size_t)(m0 + mm) * K + k0 + kk];
    }
#pragma unroll
    for (int e = 0; e < NB4; ++e) {
      const int idx4 = tid + e * 256;
      const int nn = idx4 >> 3, kq = idx4 & 7;
      rb[e] = *reinterpret_cast<const float4*>(&Bm[(size_t)nn * K + k0 + kq * 4]);
    }
  };
  auto storeAB = [&]() {
#pragma unroll
    for (int e = 0; e < 2; ++e) {
      const int idx = tid + e * 256;
      AT[(idx & 31) * 20 + (idx >> 5)] = ra[e];
    }
#pragma unroll
    for (int e = 0; e < NB4; ++e) {
      const int idx4 = tid + e * 256;
      const int nn = idx4 >> 3, kq = idx4 & 7;
      BT[(kq * 4 + 0) * BS + nn] = rb[e].x;
      BT[(kq * 4 + 1) * BS + nn] = rb[e].y;
      BT[(kq * 4 + 2) * BS + nn] = rb[e].z;
      BT[(kq * 4 + 3) * BS + nn] = rb[e].w;
    }
  };

  float acc[2][NC][4];
#pragma unroll
  for (int i = 0; i < 2; ++i)
#pragma unroll
    for (int nc = 0; nc < NC; ++nc)
#pragma unroll
      for (int j = 0; j < 4; ++j) acc[i][nc][j] = 0.f;

  loadAB(0);
  for (int k0 = 0; k0 < K; k0 += 32) {
    __syncthreads();
    storeAB();
    __syncthreads();
    if (k0 + 32 < K) loadAB(k0 + 32);
#pragma unroll
    for (int kk = 0; kk < 32; ++kk) {
      const float2 a2 = *reinterpret_cast<const float2*>(&AT[kk * 20 + tr * 2]);
#pragma unroll
      for (int nc = 0; nc < NC; ++nc) {
        const float4 b4 = *reinterpret_cast<const float4*>(
            &BT[kk * BS + nc * 128 + tc * 4]);
        acc[0][nc][0] += a2.x * b4.x; acc[0][nc][1] += a2.x * b4.y;
        acc[0][nc][2] += a2.x * b4.z; acc[0][nc][3] += a2.x * b4.w;
        acc[1][nc][0] += a2.y * b4.x; acc[1][nc][1] += a2.y * b4.y;
        acc[1][nc][2] += a2.y * b4.z; acc[1][nc][3] += a2.y * b4.w;
      }
    }
  }

#pragma unroll
  for (int i = 0; i < 2; ++i)
#pragma unroll
    for (int nc = 0; nc < NC; ++nc) {
      float4 v;
      v.x = fmaxf(acc[i][nc][0] + bias[nc * 128 + tc * 4 + 0], 0.f);
      v.y = fmaxf(acc[i][nc][1] + bias[nc * 128 + tc * 4 + 1], 0.f);
      v.z = fmaxf(acc[i][nc][2] + bias[nc * 128 + tc * 4 + 2], 0.f);
      v.w = fmaxf(acc[i][nc][3] + bias[nc * 128 + tc * 4 + 3], 0.f);
      *reinterpret_cast<float4*>(&C[(size_t)(m0 + tr * 2 + i) * NT + nc * 128 + tc * 4]) = v;
    }
}

// ------------------- fp32 64-row GEMM (tiny c4 layer) ----------------------
template <int NT>
__global__ __launch_bounds__(256) void k_rowgemm64(
    const float* __restrict__ A, const float* __restrict__ Bm,
    const float* __restrict__ bias, float* __restrict__ C, int K) {
  constexpr int NB = NT / 64;
  __shared__ float AT[32 * 68];
  __shared__ float BT[32 * (NT + 4)];
  constexpr int BS = NT + 4;
  const int m0 = blockIdx.x * 64;
  const int tid = threadIdx.x;
  const int tr = tid >> 4, tc = tid & 15;
  float acc[4][NB][4];
#pragma unroll
  for (int i = 0; i < 4; ++i)
#pragma unroll
    for (int nb = 0; nb < NB; ++nb)
#pragma unroll
      for (int j = 0; j < 4; ++j) acc[i][nb][j] = 0.f;

  for (int k0 = 0; k0 < K; k0 += 32) {
#pragma unroll
    for (int e = 0; e < 8; ++e) {
      int idx = tid + e * 256;
      int mm = idx >> 5, kk = idx & 31;
      AT[kk * 68 + mm] = A[(size_t)(m0 + mm) * K + k0 + kk];
    }
#pragma unroll
    for (int e = 0; e < NB * 8; ++e) {
      int idx = tid + e * 256;
      int nn = idx >> 5, kk = idx & 31;
      BT[kk * BS + nn] = Bm[(size_t)nn * K + k0 + kk];
    }
    __syncthreads();
#pragma unroll
    for (int kk = 0; kk < 32; ++kk) {
      const float4 a4 = *reinterpret_cast<const float4*>(&AT[kk * 68 + tr * 4]);
      const float a[4] = {a4.x, a4.y, a4.z, a4.w};
#pragma unroll
      for (int nb = 0; nb < NB; ++nb) {
        const float4 b4 = *reinterpret_cast<const float4*>(&BT[kk * BS + nb * 64 + tc * 4]);
        const float b[4] = {b4.x, b4.y, b4.z, b4.w};
#pragma unroll
        for (int i = 0; i < 4; ++i)
#pragma unroll
          for (int j = 0; j < 4; ++j) acc[i][nb][j] += a[i] * b[j];
      }
    }
    __syncthreads();
  }
#pragma unroll
  for (int i = 0; i < 4; ++i)
#pragma unroll
    for (int nb = 0; nb < NB; ++nb) {
      float4 v;
      v.x = fmaxf(acc[i][nb][0] + bias[nb * 64 + tc * 4 + 0], 0.f);
      v.y = fmaxf(acc[i][nb][1] + bias[nb * 64 + tc * 4 + 1], 0.f);
      v.z = fmaxf(acc[i][nb][2] + bias[nb * 64 + tc * 4 + 2], 0.f);
      v.w = fmaxf(acc[i][nb][3] + bias[nb * 64 + tc * 4 + 3], 0.f);
      *reinterpret_cast<float4*>(&C[(size_t)(m0 + tr * 4 + i) * NT + nb * 64 + tc * 4]) = v;
    }
}

// ---------------- weight split: fp32 -> bf16 hi/lo -------------------------
__global__ __launch_bounds__(256) void k_splitW(const float* __restrict__ W,
                                                short* __restrict__ Wh,
                                                short* __restrict__ Wl, int n) {
  const int i = blockIdx.x * 256 + threadIdx.x;
  if (i < n) {
    const float x = W[i];
    const unsigned hb = rne_bf16(x);
    const float lo = x - __uint_as_float(hb);
    Wh[i] = (short)(hb >> 16);
    Wl[i] = (short)(rne_bf16(lo) >> 16);
  }
}

// ------------------------- quantum circuit -> U (bf16 splits) --------------
__global__ __launch_bounds__(64) void k_buildU(const float* __restrict__ qw,
                                               short* __restrict__ Uh,
                                               short* __restrict__ Ul) {
  const int j = blockIdx.x;
  const int t = threadIdx.x;
  float a0 = (t == j) ? 1.f : 0.f;
  float a1 = (64 + t == j) ? 1.f : 0.f;
  float a2 = (128 + t == j) ? 1.f : 0.f;
  float a3 = (192 + t == j) ? 1.f : 0.f;
  for (int l = 0; l < 7; ++l) {
#pragma unroll
    for (int q = 0; q < 8; ++q) {
      const float th = 0.5f * qw[l * 8 + q];
      const float c = cosf(th), s = sinf(th);
      const int m = 7 - q;
      if (m == 7) {
        const float n0 = c * a0 - s * a2, n2 = s * a0 + c * a2;
        const float n1 = c * a1 - s * a3, n3 = s * a1 + c * a3;
        a0 = n0; a2 = n2; a1 = n1; a3 = n3;
      } else if (m == 6) {
        const float n0 = c * a0 - s * a1, n1 = s * a0 + c * a1;
        const float n2 = c * a2 - s * a3, n3 = s * a2 + c * a3;
        a0 = n0; a1 = n1; a2 = n2; a3 = n3;
      } else {
        const float p0 = __shfl_xor(a0, 1 << m, 64);
        const float p1 = __shfl_xor(a1, 1 << m, 64);
        const float p2 = __shfl_xor(a2, 1 << m, 64);
        const float p3 = __shfl_xor(a3, 1 << m, 64);
        const float sgn = ((t >> m) & 1) ? s : -s;
        a0 = c * a0 + sgn * p0; a1 = c * a1 + sgn * p1;
        a2 = c * a2 + sgn * p2; a3 = c * a3 + sgn * p3;
      }
    }
#pragma unroll
    for (int q = 0; q < 7; ++q) {
      const int mc = 7 - q, mt = mc - 1;
      if (mc == 7) {
        const float tmp = a2; a2 = a3; a3 = tmp;
      } else if (mc == 6) {
        a1 = __shfl_xor(a1, 32, 64);
        a3 = __shfl_xor(a3, 32, 64);
      } else {
        const float p0 = __shfl_xor(a0, 1 << mt, 64);
        const float p1 = __shfl_xor(a1, 1 << mt, 64);
        const float p2 = __shfl_xor(a2, 1 << mt, 64);
        const float p3 = __shfl_xor(a3, 1 << mt, 64);
        if ((t >> mc) & 1) { a0 = p0; a1 = p1; a2 = p2; a3 = p3; }
      }
    }
  }
  const float av[4] = {a0, a1, a2, a3};
#pragma unroll
  for (int r = 0; r < 4; ++r) {
    const float x = av[r];
    const unsigned hb = rne_bf16(x);
    const float lo = x - __uint_as_float(hb);
    Uh[(r * 64 + t) * 256 + j] = (short)(hb >> 16);
    Ul[(r * 64 + t) * 256 + j] = (short)(rne_bf16(lo) >> 16);
  }
}

// ------------------------- final layer -------------------------------------
__global__ __launch_bounds__(256) void k_head5(const float* __restrict__ h4,
                                               const float* __restrict__ w,
                                               const float* __restrict__ b,
                                               float* __restrict__ out) {
  const int row = blockIdx.x * 4 + (threadIdx.x >> 6);
  const int lane = threadIdx.x & 63;
  float s = h4[(size_t)row * 64 + lane] * w[lane];
#pragma unroll
  for (int d = 32; d > 0; d >>= 1) s += __shfl_xor(s, d, 64);
  if (lane == 0) out[row] = 1.f / (1.f + expf(-(s + b[0])));
}

// ---------------------------------------------------------------------------
extern "C" void kernel_launch(void* const* d_in, const int* in_sizes, int n_in,
                              void* d_out, int out_size, void* d_ws, size_t ws_size,
                              hipStream_t stream) {
  const float* x       = (const float*)d_in[0];
  const float* conv1_w = (const float*)d_in[1];
  const float* conv1_b = (const float*)d_in[2];
  const float* conv2_w = (const float*)d_in[3];
  const float* conv2_b = (const float*)d_in[4];
  const float* conv3_w = (const float*)d_in[5];
  const float* conv3_b = (const float*)d_in[6];
  const float* fc_w    = (const float*)d_in[7];
  const float* fc_b    = (const float*)d_in[8];
  const float* q_w     = (const float*)d_in[9];
  const float* c1_w    = (const float*)d_in[10];
  const float* c1_b    = (const float*)d_in[11];
  const float* c2_w    = (const float*)d_in[12];
  const float* c2_b    = (const float*)d_in[13];
  const float* c3_w    = (const float*)d_in[14];
  const float* c3_b    = (const float*)d_in[15];
  const float* c4_w    = (const float*)d_in[16];
  const float* c4_b    = (const float*)d_in[17];
  const float* c5_w    = (const float*)d_in[18];
  const float* c5_b    = (const float*)d_in[19];
  float* out = (float*)d_out;
  char* ws = (char*)d_ws;

  // upper region (persists across conv stage): pooled + weight splits
  float* y2p    = (float*)(ws + 0);          // 29,360,128
  float* pooled = (float*)(ws + 29360128);   //  9,437,184 (ends 38,797,312)
  short* c2h    = (short*)(ws + 38797312);   //    262,144
  short* c2l    = (short*)(ws + 39059456);   //    262,144
  short* fch    = (short*)(ws + 39321600);   //    147,456
  short* fcl    = (short*)(ws + 39469056);   //    147,456 (ends 39,616,512)
  // lower region (y2p dead after conv3pool)
  float* feat   = (float*)(ws + 0);          //  8,388,608 (unnormalized fhat)
  short* Uh     = (short*)(ws + 8388608);    //    131,072
  short* Ul     = (short*)(ws + 8519680);    //    131,072
  float* qpb    = (float*)(ws + 8650752);    //     65,536  qp[2][8192]
  float* rsb    = (float*)(ws + 8716288);    //     65,536  rs[2][8192]
  float* h2     = (float*)(ws + 8781824);    //  8,388,608 (ends 17,170,432)
  float* h3     = (float*)(ws + 17170432);   //  4,194,304
  float* h4     = (float*)(ws + 21364736);   //  2,097,152 (ends 23,461,888)
  (void)in_sizes; (void)n_in; (void)out_size; (void)ws_size;

  k_splitW<<<512, 256, 0, stream>>>(c2_w, c2h, c2l, 256 * 512);
  k_splitW<<<288, 256, 0, stream>>>(fc_w, fch, fcl, 256 * 288);

  k_conv12<<<2048, 256, 0, stream>>>(x, conv1_w, conv1_b, conv2_w, conv2_b, y2p);
  k_conv3pool<<<1024, 256, 0, stream>>>(y2p, conv3_w, conv3_b, pooled);

  // fc: feat = relu(pooled @ fc_w^T + fc_b) (UNNORMALIZED) + rs partials
  dim3 g2(512, 2);
  k_mfma2<0, 288><<<g2, 256, 0, stream>>>(pooled, fch, fcl, fc_b, feat, rsb,
                                          nullptr, nullptr, nullptr, nullptr);
  k_buildU<<<256, 64, 0, stream>>>(q_w, Uh, Ul);
  // qp partials of (feat @ U^T)^2, ny=1 negated
  k_mfma2<1, 256><<<g2, 256, 0, stream>>>(feat, Uh, Ul, nullptr, qpb, nullptr,
                                          nullptr, nullptr, nullptr, nullptr);
  // h2 = relu(relu(qm*c1w+c1b) @ c2^T + c2b), qm = (qp0+qp1)/max(rs0+rs1,eps)
  k_mfma2<2, 512><<<g2, 256, 0, stream>>>(nullptr, c2h, c2l, c2_b, h2, nullptr,
                                          qpb, rsb, c1_w, c1_b);
  // h3 = relu(h2 @ c3^T + c3b)  [fp32]
  k_rowgemm16<128, 0, false><<<512, 256, 0, stream>>>(h2, c3_w, c3_b, h3,
                                                      nullptr, nullptr, nullptr, 256);
  // h4 = relu(h3 @ c4^T + c4b)  [fp32]
  k_rowgemm64<64><<<128, 256, 0, stream>>>(h3, c4_w, c4_b, h4, 128);
  k_head5<<<2048, 256, 0, stream>>>(h4, c5_w, c5_b, out);
}